// Round 2
// baseline (343.764 us; speedup 1.0000x reference)
//
#include <hip/hip_runtime.h>
#include <math.h>

#define B  4
#define N  4096
#define C  128
#define K  16
#define NB 3

__device__ __forceinline__ float leaky(float x) {
  return x >= 0.f ? x : 0.01f * x;
}

// ---- KNN (faithful: k+1 LARGEST sq-dists, drop first) ----
// 4096 blocks x 256 threads; 4 waves per block = 4 query rows; one wave per row.
// Each lane holds 64 candidate distances in registers; 17 rounds of wave argmax
// with jax.lax.top_k tie-break (equal value -> smaller index wins).
__global__ __launch_bounds__(256) void knn_kernel(const float* __restrict__ xyz,
                                                  int* __restrict__ idxOut) {
  __shared__ float ls[3 * N];  // SoA x[4096], y[4096], z[4096] (48 KB)
  int bidx = blockIdx.x;
  int b = bidx >> 10;                 // 1024 blocks per batch
  int row0 = (bidx & 1023) << 2;      // 4 rows per block
  const float* src = xyz + b * N * 3;
  for (int e = threadIdx.x; e < 3 * N; e += 256) {
    ls[(e % 3) * N + (e / 3)] = src[e];
  }
  __syncthreads();

  int lane = threadIdx.x & 63;
  int wave = threadIdx.x >> 6;
  int i = row0 + wave;  // query point within batch

  float xi = ls[i], yi = ls[N + i], zi = ls[2 * N + i];
  // sq = (x*x + y*y) + z*z, exact f32 rounding, no FMA contraction
  float sqi = __fadd_rn(__fadd_rn(__fmul_rn(xi, xi), __fmul_rn(yi, yi)), __fmul_rn(zi, zi));

  float d[64];
  float bd = -INFINITY;
  int bt = 0;
#pragma unroll
  for (int t = 0; t < 64; ++t) {
    int j = lane + (t << 6);  // per-lane j strictly increasing with t
    float xj = ls[j], yj = ls[N + j], zj = ls[2 * N + j];
    float sqj = __fadd_rn(__fadd_rn(__fmul_rn(xj, xj), __fmul_rn(yj, yj)), __fmul_rn(zj, zj));
    float dt = __fadd_rn(__fmul_rn(xi, xj), __fmul_rn(yi, yj));
    dt = __fadd_rn(dt, __fmul_rn(zi, zj));
    // dist = (sq_i + sq_j) - 2*dot  (reference op order)
    float dd = __fsub_rn(__fadd_rn(sqi, sqj), __fmul_rn(2.0f, dt));
    d[t] = dd;
    if (dd > bd) { bd = dd; bt = t; }  // strict > keeps smallest j on tie
  }

  long long outBase = ((long long)(b * N + i)) * K;
  for (int r = 0; r <= K; ++r) {
    float wd = bd;
    int wj = lane + (bt << 6);
#pragma unroll
    for (int off = 1; off < 64; off <<= 1) {
      float od = __shfl_xor(wd, off, 64);
      int oj = __shfl_xor(wj, off, 64);
      if (od > wd || (od == wd && oj < wj)) { wd = od; wj = oj; }
    }
    if (r > 0 && lane == 0) idxOut[outBase + (r - 1)] = wj;  // r==0 dropped
    if (r == K) break;
    if (lane == (wj & 63)) {  // winner lane: invalidate + rescan (static indices)
      int wt = wj >> 6;
      bd = -INFINITY; bt = 0;
#pragma unroll
      for (int t = 0; t < 64; ++t) {
        if (t == wt) d[t] = -INFINITY;
        float dd = d[t];
        if (dd > bd) { bd = dd; bt = t; }
      }
    }
  }
}

// ---- gather-sum: S[row,c] = sum_t leaky(P[b, idx[row,t], c]) ----
__global__ __launch_bounds__(256) void gather_kernel(const float* __restrict__ P,
                                                     const int* __restrict__ idx,
                                                     float* __restrict__ S) {
  int tid = blockIdx.x * 256 + threadIdx.x;  // row*128 + c
  int row = tid >> 7;
  int c = tid & 127;
  int b = row >> 12;
  const float* Pb = P + ((long long)b << 12) * C;
  const int* ip = idx + row * K;
  float s = 0.f;
#pragma unroll
  for (int t = 0; t < K; ++t) {
    int j = ip[t];
    s += leaky(Pb[j * C + c]);
  }
  S[tid] = s;
}

// ---- fused per-block update (in place):
// P[row] = (leaky(P[row])@Wc^T + bc + S[row]@Wg^T + 16*bg)/17 + P[row]
// 512 blocks x 256 threads; each block: 32 rows, thread=(o, row-half of 16)
__global__ __launch_bounds__(256) void block_kernel(
    float* __restrict__ P, const float* __restrict__ S,
    const float* __restrict__ Wc, const float* __restrict__ bc,
    const float* __restrict__ Wg, const float* __restrict__ bg) {
  __shared__ float Al[32][128];
  __shared__ float Sl[32][128];
  int row0 = blockIdx.x * 32;
  for (int e = threadIdx.x; e < 32 * 128; e += 256) {
    int r = e >> 7, c = e & 127;
    float pv = P[(row0 + r) * C + c];
    Al[r][c] = leaky(pv);
    Sl[r][c] = S[(row0 + r) * C + c];
  }
  __syncthreads();

  int o = threadIdx.x & 127;
  int rh = (threadIdx.x >> 7) << 4;  // 0 or 16
  float acc[16];
#pragma unroll
  for (int r = 0; r < 16; ++r) acc[r] = 0.f;

  const float* wcRow = Wc + o * C;
  const float* wgRow = Wg + o * C;
  for (int c0 = 0; c0 < C; c0 += 4) {
    float4 wc4 = *(const float4*)(wcRow + c0);
    float4 wg4 = *(const float4*)(wgRow + c0);
#pragma unroll
    for (int r = 0; r < 16; ++r) {
      float4 a  = *(const float4*)&Al[rh + r][c0];
      float4 s4 = *(const float4*)&Sl[rh + r][c0];
      acc[r] += wc4.x * a.x + wc4.y * a.y + wc4.z * a.z + wc4.w * a.w
              + wg4.x * s4.x + wg4.y * s4.y + wg4.z * s4.z + wg4.w * s4.w;
    }
  }

  float bcv = bc[o];
  float bgv = bg[o];
#pragma unroll
  for (int r = 0; r < 16; ++r) {
    int row = row0 + rh + r;
    float sc = P[row * C + o];
    P[row * C + o] = (acc[r] + bcv + 16.0f * bgv) / 17.0f + sc;
  }
}

extern "C" void kernel_launch(void* const* d_in, const int* in_sizes, int n_in,
                              void* d_out, int out_size, void* d_ws, size_t ws_size,
                              hipStream_t stream) {
  const float* xyz = (const float*)d_in[0];
  const float* pts = (const float*)d_in[1];
  // d_in[2..4] = k, n_cout, n_blocks (known constants: 16, 128, 3)
  const float* Wc = (const float*)d_in[5];
  const float* bc = (const float*)d_in[6];
  const float* Wg = (const float*)d_in[7];
  const float* bg = (const float*)d_in[8];

  const size_t PE = (size_t)B * N * C;  // 2097152 elements
  float* P  = (float*)d_out;            // points state lives in d_out (f32), in-place
  int* idx  = (int*)d_ws;               // 1 MB
  float* Sb = (float*)((char*)d_ws + (size_t)B * N * K * sizeof(int));  // 8 MB

  // P := points (f32 d2d copy; capture-legal)
  hipMemcpyAsync(P, pts, PE * sizeof(float), hipMemcpyDeviceToDevice, stream);

  hipLaunchKernelGGL(knn_kernel, dim3(4096), dim3(256), 0, stream, xyz, idx);

  for (int i = 0; i < NB; ++i) {
    hipLaunchKernelGGL(gather_kernel, dim3(PE / 256), dim3(256), 0, stream, P, idx, Sb);
    hipLaunchKernelGGL(block_kernel, dim3((B * N) / 32), dim3(256), 0, stream,
                       P, Sb, Wc + (size_t)i * C * C, bc + (size_t)i * C,
                       Wg + (size_t)i * C * C, bg + (size_t)i * C);
  }
}

// Round 3
// 235.516 us; speedup vs baseline: 1.4596x; 1.4596x over previous
//
#include <hip/hip_runtime.h>
#include <math.h>

#define B  4
#define N  4096
#define C  128
#define K  16
#define NB 3

__device__ __forceinline__ float leaky(float x) {
  return x >= 0.f ? x : 0.01f * x;
}

// ---- KNN (faithful: k+1 LARGEST sq-dists, drop first) ----
// 2048 blocks x 512 threads; 8 waves per block = 8 query rows; one wave per row.
// Points staged in LDS as float4(x,y,z,sq) -> one ds_read_b128 per candidate.
// Each lane holds 64 candidates in registers, tracked as 8 groups of 8 with
// cached group argmax. Extraction: wave butterfly argmax (tie -> smaller j),
// then SCALAR-branch rescan of only the winner's group (8+8 iters, not 64).
__global__ __launch_bounds__(512) void knn_kernel(const float* __restrict__ xyz,
                                                  int* __restrict__ idxOut) {
  __shared__ float4 p[N];  // 64 KB
  int bidx = blockIdx.x;
  int b = bidx >> 9;                  // 512 blocks per batch
  int row0 = (bidx & 511) << 3;       // 8 rows per block
  const float* src = xyz + b * N * 3;
  for (int e = threadIdx.x; e < N; e += 512) {
    float x = src[3 * e], y = src[3 * e + 1], z = src[3 * e + 2];
    // sq = (x*x + y*y) + z*z, exact f32 rounding, no FMA contraction
    float sq = __fadd_rn(__fadd_rn(__fmul_rn(x, x), __fmul_rn(y, y)), __fmul_rn(z, z));
    p[e] = make_float4(x, y, z, sq);
  }
  __syncthreads();

  int lane = threadIdx.x & 63;
  int wave = threadIdx.x >> 6;
  int i = row0 + wave;  // query point within batch

  float4 pi = p[i];
  float xi = pi.x, yi = pi.y, zi = pi.z, sqi = pi.w;

  float d[64];
  float gm[8];
  int gt[8];
#pragma unroll
  for (int g = 0; g < 8; ++g) { gm[g] = -INFINITY; gt[g] = 0; }

#pragma unroll
  for (int t = 0; t < 64; ++t) {
    int j = lane + (t << 6);  // per-lane j strictly increasing with t
    float4 pj = p[j];
    // dist = (sq_i + sq_j) - 2*dot  (reference op order, no contraction)
    float dt = __fadd_rn(__fmul_rn(xi, pj.x), __fmul_rn(yi, pj.y));
    dt = __fadd_rn(dt, __fmul_rn(zi, pj.z));
    float dd = __fsub_rn(__fadd_rn(sqi, pj.w), __fmul_rn(2.0f, dt));
    d[t] = dd;
    int g = t >> 3;
    if (dd > gm[g]) { gm[g] = dd; gt[g] = t; }  // strict > : smallest t on tie
  }
  float bd = -INFINITY;
  int bt = 0;
#pragma unroll
  for (int g = 0; g < 8; ++g) {
    if (gm[g] > bd) { bd = gm[g]; bt = gt[g]; }  // ascending g : smallest t on tie
  }

  long long outBase = ((long long)(b * N + i)) * K;
  for (int r = 0; r <= K; ++r) {
    // wave-wide argmax, tie-break: smaller global index j wins
    float wd = bd;
    int wj = lane + (bt << 6);
#pragma unroll
    for (int off = 1; off < 64; off <<= 1) {
      float od = __shfl_xor(wd, off, 64);
      int oj = __shfl_xor(wj, off, 64);
      if (od > wd || (od == wd && oj < wj)) { wd = od; wj = oj; }
    }
    if (r > 0 && lane == 0) idxOut[outBase + (r - 1)] = wj;  // r==0 dropped
    if (r == K) break;

    // winner is wave-uniform -> hoist to SGPR, scalar-branch to its group only
    int s_wj = __builtin_amdgcn_readfirstlane(wj);
    int s_wl = s_wj & 63;        // winner lane
    int s_wt = s_wj >> 6;        // winner slot t
    int s_wg = s_wt >> 3;        // winner group
    int s_we = s_wt & 7;         // slot within group
    bool amW = (lane == s_wl);
#pragma unroll
    for (int g = 0; g < 8; ++g) {
      if (g == s_wg) {  // scalar condition -> s_cbranch skips 7 groups
        float nm = -INFINITY;
        int nt = 0;
#pragma unroll
        for (int e = 0; e < 8; ++e) {
          int t = g * 8 + e;
          float dv = d[t];
          if (amW && (e == s_we)) dv = -INFINITY;  // invalidate extracted elem
          d[t] = dv;
          if (dv > nm) { nm = dv; nt = t; }
        }
        if (amW) { gm[g] = nm; gt[g] = nt; }
      }
    }
    bd = -INFINITY; bt = 0;
#pragma unroll
    for (int g = 0; g < 8; ++g) {
      if (gm[g] > bd) { bd = gm[g]; bt = gt[g]; }
    }
  }
}

// ---- gather-sum: S[row,c] = sum_t leaky(P[b, idx[row,t], c]) ----
__global__ __launch_bounds__(256) void gather_kernel(const float* __restrict__ P,
                                                     const int* __restrict__ idx,
                                                     float* __restrict__ S) {
  int tid = blockIdx.x * 256 + threadIdx.x;  // row*128 + c
  int row = tid >> 7;
  int c = tid & 127;
  int b = row >> 12;
  const float* Pb = P + ((long long)b << 12) * C;
  const int* ip = idx + row * K;
  float s = 0.f;
#pragma unroll
  for (int t = 0; t < K; ++t) {
    int j = ip[t];
    s += leaky(Pb[j * C + c]);
  }
  S[tid] = s;
}

// ---- fused per-block update (in place):
// P[row] = (leaky(P[row])@Wc^T + bc + S[row]@Wg^T + 16*bg)/17 + P[row]
__global__ __launch_bounds__(256) void block_kernel(
    float* __restrict__ P, const float* __restrict__ S,
    const float* __restrict__ Wc, const float* __restrict__ bc,
    const float* __restrict__ Wg, const float* __restrict__ bg) {
  __shared__ float Al[32][128];
  __shared__ float Sl[32][128];
  int row0 = blockIdx.x * 32;
  for (int e = threadIdx.x; e < 32 * 128; e += 256) {
    int r = e >> 7, c = e & 127;
    float pv = P[(row0 + r) * C + c];
    Al[r][c] = leaky(pv);
    Sl[r][c] = S[(row0 + r) * C + c];
  }
  __syncthreads();

  int o = threadIdx.x & 127;
  int rh = (threadIdx.x >> 7) << 4;  // 0 or 16
  float acc[16];
#pragma unroll
  for (int r = 0; r < 16; ++r) acc[r] = 0.f;

  const float* wcRow = Wc + o * C;
  const float* wgRow = Wg + o * C;
  for (int c0 = 0; c0 < C; c0 += 4) {
    float4 wc4 = *(const float4*)(wcRow + c0);
    float4 wg4 = *(const float4*)(wgRow + c0);
#pragma unroll
    for (int r = 0; r < 16; ++r) {
      float4 a  = *(const float4*)&Al[rh + r][c0];
      float4 s4 = *(const float4*)&Sl[rh + r][c0];
      acc[r] += wc4.x * a.x + wc4.y * a.y + wc4.z * a.z + wc4.w * a.w
              + wg4.x * s4.x + wg4.y * s4.y + wg4.z * s4.z + wg4.w * s4.w;
    }
  }

  float bcv = bc[o];
  float bgv = bg[o];
#pragma unroll
  for (int r = 0; r < 16; ++r) {
    int row = row0 + rh + r;
    float sc = P[row * C + o];
    P[row * C + o] = (acc[r] + bcv + 16.0f * bgv) / 17.0f + sc;
  }
}

extern "C" void kernel_launch(void* const* d_in, const int* in_sizes, int n_in,
                              void* d_out, int out_size, void* d_ws, size_t ws_size,
                              hipStream_t stream) {
  const float* xyz = (const float*)d_in[0];
  const float* pts = (const float*)d_in[1];
  // d_in[2..4] = k, n_cout, n_blocks (known constants: 16, 128, 3)
  const float* Wc = (const float*)d_in[5];
  const float* bc = (const float*)d_in[6];
  const float* Wg = (const float*)d_in[7];
  const float* bg = (const float*)d_in[8];

  const size_t PE = (size_t)B * N * C;  // 2097152 elements
  float* P  = (float*)d_out;            // points state lives in d_out (f32), in-place
  int* idx  = (int*)d_ws;               // 1 MB
  float* Sb = (float*)((char*)d_ws + (size_t)B * N * K * sizeof(int));  // 8 MB

  // P := points (f32 d2d copy; capture-legal)
  hipMemcpyAsync(P, pts, PE * sizeof(float), hipMemcpyDeviceToDevice, stream);

  hipLaunchKernelGGL(knn_kernel, dim3(2048), dim3(512), 0, stream, xyz, idx);

  for (int i = 0; i < NB; ++i) {
    hipLaunchKernelGGL(gather_kernel, dim3(PE / 256), dim3(256), 0, stream, P, idx, Sb);
    hipLaunchKernelGGL(block_kernel, dim3((B * N) / 32), dim3(256), 0, stream,
                       P, Sb, Wc + (size_t)i * C * C, bc + (size_t)i * C,
                       Wg + (size_t)i * C * C, bg + (size_t)i * C);
  }
}

// Round 5
// 188.954 us; speedup vs baseline: 1.8193x; 1.2464x over previous
//
#include <hip/hip_runtime.h>
#include <math.h>

#define B  4
#define N  4096
#define C  128
#define K  16
#define NB 3
#define CH 2048  // knn LDS chunk (points)

typedef unsigned int u32;
typedef unsigned long long u64;
typedef __attribute__((ext_vector_type(8))) short short8_t;
typedef __attribute__((ext_vector_type(4))) float f32x4;

__device__ __forceinline__ float leaky(float x) {
  return x >= 0.f ? x : 0.01f * x;
}
__device__ __forceinline__ unsigned short f2bf(float f) {
  u32 x = __float_as_uint(f);
  return (unsigned short)((x + 0x7FFFu + ((x >> 16) & 1u)) >> 16);  // RNE
}
__device__ __forceinline__ float bflo(u32 u) { return __uint_as_float(u << 16); }
__device__ __forceinline__ float bfhi(u32 u) { return __uint_as_float(u & 0xFFFF0000u); }

// ---- KNN (faithful: k+1 LARGEST sq-dists, drop first) ----
// 2048 blocks x 512 threads; 8 waves = 8 query rows; one wave per row.
// Cloud staged in TWO 32KB chunks (occupancy: LDS no longer caps blocks/CU).
// Distances kept as monotone-encoded u32; butterfly argmax on u64 key
// (enc<<32)|(4095-j) -> tie automatically picks smaller j (jax top_k order).
__global__ __launch_bounds__(512) void knn_kernel(const float* __restrict__ xyz,
                                                  int* __restrict__ idxOut) {
  __shared__ float4 p[CH];  // 32 KB
  int bidx = blockIdx.x;
  int b = bidx >> 9;                  // 512 blocks per batch
  int row0 = (bidx & 511) << 3;       // 8 rows per block
  const float* src = xyz + b * N * 3;

  int lane = threadIdx.x & 63;
  int wave = threadIdx.x >> 6;
  int i = row0 + wave;  // query point within batch

  float xi = src[3 * i], yi = src[3 * i + 1], zi = src[3 * i + 2];
  // sq = (x*x + y*y) + z*z, exact f32 rounding, no FMA contraction
  float sqi = __fadd_rn(__fadd_rn(__fmul_rn(xi, xi), __fmul_rn(yi, yi)), __fmul_rn(zi, zi));

  u32 d_enc[64];
  u32 gm[8];
  int gt[8];
#pragma unroll
  for (int g = 0; g < 8; ++g) { gm[g] = 0u; gt[g] = g * 8; }

#pragma unroll
  for (int ch = 0; ch < 2; ++ch) {
    __syncthreads();  // protect previous chunk's reads before overwrite
    for (int e = threadIdx.x; e < CH; e += 512) {
      int gj = (ch << 11) + e;
      float x = src[3 * gj], y = src[3 * gj + 1], z = src[3 * gj + 2];
      float sq = __fadd_rn(__fadd_rn(__fmul_rn(x, x), __fmul_rn(y, y)), __fmul_rn(z, z));
      p[e] = make_float4(x, y, z, sq);
    }
    __syncthreads();
#pragma unroll
    for (int t2 = 0; t2 < 32; ++t2) {
      int t = (ch << 5) + t2;          // global slot, compile-time
      float4 pj = p[lane + (t2 << 6)];
      // dist = (sq_i + sq_j) - 2*dot  (reference op order, no contraction)
      float dt = __fadd_rn(__fmul_rn(xi, pj.x), __fmul_rn(yi, pj.y));
      dt = __fadd_rn(dt, __fmul_rn(zi, pj.z));
      float dd = __fsub_rn(__fadd_rn(sqi, pj.w), __fmul_rn(2.0f, dt));
      u32 bits = __float_as_uint(dd);
      u32 enc = bits ^ ((u32)(((int)bits) >> 31) | 0x80000000u);  // monotone
      d_enc[t] = enc;
      int g = t >> 3;
      if (enc > gm[g]) { gm[g] = enc; gt[g] = t; }  // strict > : smallest t on tie
    }
  }

  u32 benc = 0u; int bt = 0;
#pragma unroll
  for (int g = 0; g < 8; ++g) {
    if (gm[g] > benc) { benc = gm[g]; bt = gt[g]; }
  }

  long long outBase = ((long long)(b * N + i)) * K;
  for (int r = 0; r <= K; ++r) {
    // wave-wide argmax on packed key; tie-break: smaller j wins
    u64 key = ((u64)benc << 32) | (u32)(4095 - (lane + (bt << 6)));
#pragma unroll
    for (int off = 1; off < 64; off <<= 1) {
      u64 ok = __shfl_xor(key, off, 64);
      key = (ok > key) ? ok : key;
    }
    int wj = 4095 - (int)(key & 0xFFFFFFFFull);
    if (r > 0 && lane == 0) idxOut[outBase + (r - 1)] = wj;  // r==0 dropped
    if (r == K) break;

    // winner is wave-uniform -> SGPR, scalar-branch rescan of its group only
    int s_wj = __builtin_amdgcn_readfirstlane(wj);
    int s_wl = s_wj & 63;
    int s_wt = s_wj >> 6;
    int s_wg = s_wt >> 3;
    int s_we = s_wt & 7;
    bool amW = (lane == s_wl);
#pragma unroll
    for (int g = 0; g < 8; ++g) {
      if (g == s_wg) {
        u32 nm = 0u; int nt = g * 8;
#pragma unroll
        for (int e = 0; e < 8; ++e) {
          int t = g * 8 + e;
          u32 dv = d_enc[t];
          if (amW && (e == s_we)) dv = 0u;  // invalidate extracted element
          d_enc[t] = dv;
          if (dv > nm) { nm = dv; nt = t; }
        }
        if (amW) { gm[g] = nm; gt[g] = nt; }
      }
    }
    benc = 0u; bt = 0;
#pragma unroll
    for (int g = 0; g < 8; ++g) {
      if (gm[g] > benc) { benc = gm[g]; bt = gt[g]; }
    }
  }
}

// ---- Abf = bf16(leaky(P)) : 8 elems/thread ----
__global__ __launch_bounds__(256) void cvtA_kernel(const float* __restrict__ P,
                                                   unsigned short* __restrict__ Abf) {
  int e8 = blockIdx.x * 256 + threadIdx.x;
  const float4* p4 = (const float4*)(P + (size_t)e8 * 8);
  float4 a = p4[0], c = p4[1];
  unsigned short u0 = f2bf(leaky(a.x)), u1 = f2bf(leaky(a.y));
  unsigned short u2 = f2bf(leaky(a.z)), u3 = f2bf(leaky(a.w));
  unsigned short u4 = f2bf(leaky(c.x)), u5 = f2bf(leaky(c.y));
  unsigned short u6 = f2bf(leaky(c.z)), u7 = f2bf(leaky(c.w));
  uint4 o;
  o.x = (u32)u0 | ((u32)u1 << 16);
  o.y = (u32)u2 | ((u32)u3 << 16);
  o.z = (u32)u4 | ((u32)u5 << 16);
  o.w = (u32)u6 | ((u32)u7 << 16);
  *(uint4*)(Abf + (size_t)e8 * 8) = o;
}

// ---- W (f32) -> bf16, all 3 blocks at once ----
__global__ __launch_bounds__(256) void cvtW_kernel(const float* __restrict__ Wc,
                                                   const float* __restrict__ Wg,
                                                   unsigned short* __restrict__ Wbf) {
  int e = blockIdx.x * 256 + threadIdx.x;  // 0..98303
  if (e < NB * C * C) Wbf[e] = f2bf(Wc[e]);
  else Wbf[e] = f2bf(Wg[e - NB * C * C]);
}

// ---- fused per-block-iter: gather-sum (bf16) + dual MFMA matmul + epilogue
// grid 1024 x 256 threads (4 waves). Each workgroup: 16 rows x 128 cols out.
// out[r][o] = (leaky(P)[r]@Wc[o] + S[r]@Wg[o] + bc[o] + 16*bg[o])/17 + P[r][o]
__global__ __launch_bounds__(256) void fused_kernel(
    const float* __restrict__ Pcur, const unsigned short* __restrict__ Abf,
    const int* __restrict__ idx,
    const unsigned short* __restrict__ Wcbf, const unsigned short* __restrict__ Wgbf,
    const float* __restrict__ bc, const float* __restrict__ bg,
    float* __restrict__ Pnxt) {
  __shared__ int ji[256];
  __shared__ unsigned short Sl[16][136];  // +8 pad: 272B row stride, 16B aligned
  int row0 = blockIdx.x * 16;
  int tid = threadIdx.x;
  ji[tid] = idx[row0 * K + tid];
  __syncthreads();

  // batch base for neighbor indices (idx entries are within-batch!)
  const unsigned short* AbfB = Abf + ((size_t)(row0 >> 12) << 12) * C;

  // gather: thread (r,g) sums 8 cols [g*8, g*8+8) of row r over 16 neighbors
  {
    int r = tid >> 4, g = tid & 15;
    float s0 = 0.f, s1 = 0.f, s2 = 0.f, s3 = 0.f, s4 = 0.f, s5 = 0.f, s6 = 0.f, s7 = 0.f;
#pragma unroll
    for (int t = 0; t < K; ++t) {
      int j = ji[(r << 4) + t];
      uint4 v = *(const uint4*)(AbfB + (size_t)j * C + g * 8);
      s0 += bflo(v.x); s1 += bfhi(v.x);
      s2 += bflo(v.y); s3 += bfhi(v.y);
      s4 += bflo(v.z); s5 += bfhi(v.z);
      s6 += bflo(v.w); s7 += bfhi(v.w);
    }
    uint4 o;
    o.x = (u32)f2bf(s0) | ((u32)f2bf(s1) << 16);
    o.y = (u32)f2bf(s2) | ((u32)f2bf(s3) << 16);
    o.z = (u32)f2bf(s4) | ((u32)f2bf(s5) << 16);
    o.w = (u32)f2bf(s6) | ((u32)f2bf(s7) << 16);
    *(uint4*)(&Sl[r][g * 8]) = o;
  }
  __syncthreads();

  // MFMA: A row = lane&15, k-chunk = (lane>>4)*8 ; B col = lane&15, same k-chunk
  int lane = tid & 63, wave = tid >> 6;
  int lrow = lane & 15;
  int kgrp = (lane >> 4) * 8;
  f32x4 acc0 = {0.f, 0.f, 0.f, 0.f};
  f32x4 acc1 = {0.f, 0.f, 0.f, 0.f};
  int ct0 = wave * 2, ct1 = ct0 + 1;
  const unsigned short* abase = Abf + (size_t)(row0 + lrow) * C + kgrp;
  const unsigned short* wc0 = Wcbf + (size_t)(ct0 * 16 + lrow) * C + kgrp;
  const unsigned short* wc1 = Wcbf + (size_t)(ct1 * 16 + lrow) * C + kgrp;
  const unsigned short* wg0 = Wgbf + (size_t)(ct0 * 16 + lrow) * C + kgrp;
  const unsigned short* wg1 = Wgbf + (size_t)(ct1 * 16 + lrow) * C + kgrp;
#pragma unroll
  for (int ks = 0; ks < 4; ++ks) {
    short8_t a = *(const short8_t*)(abase + ks * 32);
    short8_t b0 = *(const short8_t*)(wc0 + ks * 32);
    short8_t b1 = *(const short8_t*)(wc1 + ks * 32);
    acc0 = __builtin_amdgcn_mfma_f32_16x16x32_bf16(a, b0, acc0, 0, 0, 0);
    acc1 = __builtin_amdgcn_mfma_f32_16x16x32_bf16(a, b1, acc1, 0, 0, 0);
  }
#pragma unroll
  for (int ks = 0; ks < 4; ++ks) {
    short8_t sf = *(const short8_t*)(&Sl[lrow][kgrp + ks * 32]);
    short8_t b0 = *(const short8_t*)(wg0 + ks * 32);
    short8_t b1 = *(const short8_t*)(wg1 + ks * 32);
    acc0 = __builtin_amdgcn_mfma_f32_16x16x32_bf16(sf, b0, acc0, 0, 0, 0);
    acc1 = __builtin_amdgcn_mfma_f32_16x16x32_bf16(sf, b1, acc1, 0, 0, 0);
  }

  // epilogue: D row=(lane>>4)*4+q, col=lane&15 (within 16x16 tile)
#pragma unroll
  for (int side = 0; side < 2; ++side) {
    int col = (side == 0 ? ct0 : ct1) * 16 + lrow;
    float bias = bc[col] + 16.0f * bg[col];
    f32x4 acc = (side == 0) ? acc0 : acc1;
#pragma unroll
    for (int q = 0; q < 4; ++q) {
      int row = row0 + (lane >> 4) * 4 + q;
      float v = (acc[q] + bias) * (1.0f / 17.0f);
      Pnxt[(size_t)row * C + col] = v + Pcur[(size_t)row * C + col];
    }
  }
}

extern "C" void kernel_launch(void* const* d_in, const int* in_sizes, int n_in,
                              void* d_out, int out_size, void* d_ws, size_t ws_size,
                              hipStream_t stream) {
  const float* xyz = (const float*)d_in[0];
  const float* pts = (const float*)d_in[1];
  const float* Wc = (const float*)d_in[5];
  const float* bc = (const float*)d_in[6];
  const float* Wg = (const float*)d_in[7];
  const float* bg = (const float*)d_in[8];

  const size_t PE = (size_t)B * N * C;  // 2097152 elements
  char* ws = (char*)d_ws;
  float* Pa            = (float*)ws;                       // 8 MB
  int* idx             = (int*)(ws + (PE * 4));            // 1 MB
  unsigned short* Abf  = (unsigned short*)(ws + PE * 4 + (size_t)B * N * K * 4);  // 4 MB
  unsigned short* Wbf  = (unsigned short*)(ws + PE * 4 + (size_t)B * N * K * 4 + PE * 2);
  unsigned short* Wcbf = Wbf;
  unsigned short* Wgbf = Wbf + (size_t)NB * C * C;

  hipLaunchKernelGGL(cvtW_kernel, dim3((2 * NB * C * C) / 256), dim3(256), 0, stream,
                     Wc, Wg, Wbf);
  hipMemcpyAsync(Pa, pts, PE * sizeof(float), hipMemcpyDeviceToDevice, stream);
  hipLaunchKernelGGL(knn_kernel, dim3(2048), dim3(512), 0, stream, xyz, idx);

  float* cur = Pa;
  float* nxt = (float*)d_out;
  for (int i = 0; i < NB; ++i) {
    hipLaunchKernelGGL(cvtA_kernel, dim3(PE / 8 / 256), dim3(256), 0, stream, cur, Abf);
    hipLaunchKernelGGL(fused_kernel, dim3((B * N) / 16), dim3(256), 0, stream,
                       cur, Abf, idx, Wcbf + (size_t)i * C * C, Wgbf + (size_t)i * C * C,
                       bc + (size_t)i * C, bg + (size_t)i * C, nxt);
    float* tmp = cur; cur = nxt; nxt = tmp;
  }
}

// Round 6
// 167.119 us; speedup vs baseline: 2.0570x; 1.1307x over previous
//
#include <hip/hip_runtime.h>
#include <math.h>

#define B  4
#define N  4096
#define C  128
#define K  16
#define NB 3

typedef unsigned int u32;
typedef unsigned long long u64;
typedef __attribute__((ext_vector_type(8))) short short8_t;
typedef __attribute__((ext_vector_type(4))) float f32x4;

__device__ __forceinline__ float leaky(float x) {
  return x >= 0.f ? x : 0.01f * x;
}
__device__ __forceinline__ unsigned short f2bf(float f) {
  u32 x = __float_as_uint(f);
  return (unsigned short)((x + 0x7FFFu + ((x >> 16) & 1u)) >> 16);  // RNE
}
__device__ __forceinline__ float bflo(u32 u) { return __uint_as_float(u << 16); }
__device__ __forceinline__ float bfhi(u32 u) { return __uint_as_float(u & 0xFFFF0000u); }

// ---- KNN (faithful: k+1 LARGEST sq-dists, drop first) ----
// 2048 blocks x 1024 threads (16 waves). 8 rows/block; TWO waves per row, each
// covering 2048 candidates = 32/lane (VGPR ~60 -> 8 waves/SIMD possible).
// Cloud staged once in 64KB LDS as float4(x,y,z,sq). Each wave extracts its
// half's top-17 as monotone-encoded u64 keys (enc<<32)|(4095-j); per-row merge
// = 64-lane bitonic sort (descending) of the 34 keys; ranks 1..16 are output
// (rank 0 = the dropped max). Key order == jax top_k (value desc, index asc).
__global__ __launch_bounds__(1024, 4) void knn_kernel(const float* __restrict__ xyz,
                                                      int* __restrict__ idxOut) {
  __shared__ float4 p[N];          // 64 KB
  __shared__ u64 mkeys[8][2][17];  // 2176 B
  int bidx = blockIdx.x;
  int b = bidx >> 9;               // 512 blocks per batch
  int row0 = (bidx & 511) << 3;    // 8 rows per block
  const float* src = xyz + b * N * 3;
  int tid = threadIdx.x;

  for (int e = tid; e < N; e += 1024) {
    float x = src[3 * e], y = src[3 * e + 1], z = src[3 * e + 2];
    // sq = (x*x + y*y) + z*z, exact f32 rounding, no FMA contraction
    float sq = __fadd_rn(__fadd_rn(__fmul_rn(x, x), __fmul_rn(y, y)), __fmul_rn(z, z));
    p[e] = make_float4(x, y, z, sq);
  }
  __syncthreads();

  int lane = tid & 63;
  int wave = tid >> 6;   // 0..15
  int rl = wave >> 1;    // local row 0..7
  int h = wave & 1;      // half: candidates [h*2048, h*2048+2048)
  int i = row0 + rl;     // query point within batch

  float4 pi = p[i];
  float xi = pi.x, yi = pi.y, zi = pi.z, sqi = pi.w;

  u32 denc[32];
  u32 gm[4];
  int gt[4];
#pragma unroll
  for (int g = 0; g < 4; ++g) { gm[g] = 0u; gt[g] = g * 8; }

#pragma unroll
  for (int t = 0; t < 32; ++t) {
    int j = (h << 11) + lane + (t << 6);
    float4 pj = p[j];
    // dist = (sq_i + sq_j) - 2*dot  (reference op order, no contraction)
    float dt = __fadd_rn(__fmul_rn(xi, pj.x), __fmul_rn(yi, pj.y));
    dt = __fadd_rn(dt, __fmul_rn(zi, pj.z));
    float dd = __fsub_rn(__fadd_rn(sqi, pj.w), __fmul_rn(2.0f, dt));
    u32 bits = __float_as_uint(dd);
    u32 enc = bits ^ ((u32)(((int)bits) >> 31) | 0x80000000u);  // monotone
    denc[t] = enc;
    int g = t >> 3;
    if (enc > gm[g]) { gm[g] = enc; gt[g] = t; }  // strict > : smallest t on tie
  }

  u32 benc = 0u; int bt = 0;
#pragma unroll
  for (int g = 0; g < 4; ++g) {
    if (gm[g] > benc) { benc = gm[g]; bt = gt[g]; }
  }

  // 17 extractions of this half's max; all stored for the merge
  for (int r = 0; r < 17; ++r) {
    u64 key = ((u64)benc << 32) | (u32)(4095 - ((h << 11) + lane + (bt << 6)));
#pragma unroll
    for (int off = 1; off < 64; off <<= 1) {
      u64 ok = __shfl_xor(key, off, 64);
      key = (ok > key) ? ok : key;
    }
    if (lane == 0) mkeys[rl][h][r] = key;
    if (r == 16) break;

    int wj = 4095 - (int)(u32)key;  // winner's global j (within batch)
    int s_wj = __builtin_amdgcn_readfirstlane(wj);
    int s_wl = s_wj & 63;           // winner lane
    int s_wt = (s_wj >> 6) & 31;    // winner slot t
    int s_wg = s_wt >> 3;
    int s_we = s_wt & 7;
    bool amW = (lane == s_wl);
#pragma unroll
    for (int g = 0; g < 4; ++g) {
      if (g == s_wg) {  // scalar branch: rescan only winner's group
        u32 nm = 0u; int nt = g * 8;
#pragma unroll
        for (int e = 0; e < 8; ++e) {
          int t = g * 8 + e;
          u32 dv = denc[t];
          if (amW && (e == s_we)) dv = 0u;  // invalidate extracted element
          denc[t] = dv;
          if (dv > nm) { nm = dv; nt = t; }
        }
        if (amW) { gm[g] = nm; gt[g] = nt; }
      }
    }
    benc = 0u; bt = 0;
#pragma unroll
    for (int g = 0; g < 4; ++g) {
      if (gm[g] > benc) { benc = gm[g]; bt = gt[g]; }
    }
  }
  __syncthreads();

  // merge: wave w (<8) sorts row w's 34 keys descending; lanes 1..16 emit
  if (wave < 8) {
    u64 key = 0;
    if (lane < 17) key = mkeys[wave][0][lane];
    else if (lane < 34) key = mkeys[wave][1][lane - 17];
#pragma unroll
    for (int k = 2; k <= 64; k <<= 1) {
#pragma unroll
      for (int j = k >> 1; j > 0; j >>= 1) {
        u64 ok = __shfl_xor(key, j, 64);
        bool keepMax = ((lane & j) == 0) == ((lane & k) == 0);
        bool ogt = ok > key;
        key = (keepMax == ogt) ? ok : key;
      }
    }
    if (lane >= 1 && lane < 17) {
      int j = 4095 - (int)(u32)key;
      idxOut[((long long)(b * N + row0 + wave)) * K + lane - 1] = j;
    }
  }
}

// ---- Abf = bf16(leaky(P)) : 8 elems/thread ----
__global__ __launch_bounds__(256) void cvtA_kernel(const float* __restrict__ P,
                                                   unsigned short* __restrict__ Abf) {
  int e8 = blockIdx.x * 256 + threadIdx.x;
  const float4* p4 = (const float4*)(P + (size_t)e8 * 8);
  float4 a = p4[0], c = p4[1];
  unsigned short u0 = f2bf(leaky(a.x)), u1 = f2bf(leaky(a.y));
  unsigned short u2 = f2bf(leaky(a.z)), u3 = f2bf(leaky(a.w));
  unsigned short u4 = f2bf(leaky(c.x)), u5 = f2bf(leaky(c.y));
  unsigned short u6 = f2bf(leaky(c.z)), u7 = f2bf(leaky(c.w));
  uint4 o;
  o.x = (u32)u0 | ((u32)u1 << 16);
  o.y = (u32)u2 | ((u32)u3 << 16);
  o.z = (u32)u4 | ((u32)u5 << 16);
  o.w = (u32)u6 | ((u32)u7 << 16);
  *(uint4*)(Abf + (size_t)e8 * 8) = o;
}

// ---- W (f32) -> bf16, all 3 blocks at once ----
__global__ __launch_bounds__(256) void cvtW_kernel(const float* __restrict__ Wc,
                                                   const float* __restrict__ Wg,
                                                   unsigned short* __restrict__ Wbf) {
  int e = blockIdx.x * 256 + threadIdx.x;  // 0..98303
  if (e < NB * C * C) Wbf[e] = f2bf(Wc[e]);
  else Wbf[e] = f2bf(Wg[e - NB * C * C]);
}

// ---- fused per-block-iter: gather-sum (bf16) + dual MFMA matmul + epilogue
// grid 1024 x 256 threads (4 waves). Each workgroup: 16 rows x 128 cols out.
// out[r][o] = (leaky(P)[r]@Wc[o] + S[r]@Wg[o] + bc[o] + 16*bg[o])/17 + P[r][o]
// If AbfN != null also emits bf16(leaky(out)) for the next iteration.
__global__ __launch_bounds__(256) void fused_kernel(
    const float* __restrict__ Pcur, const unsigned short* __restrict__ Abf,
    const int* __restrict__ idx,
    const unsigned short* __restrict__ Wcbf, const unsigned short* __restrict__ Wgbf,
    const float* __restrict__ bc, const float* __restrict__ bg,
    float* __restrict__ Pnxt, unsigned short* __restrict__ AbfN) {
  __shared__ int ji[256];
  __shared__ unsigned short Sl[16][136];  // +8 pad: 272B row stride, 16B aligned
  int row0 = blockIdx.x * 16;
  int tid = threadIdx.x;
  ji[tid] = idx[row0 * K + tid];
  __syncthreads();

  // batch base for neighbor indices (idx entries are within-batch!)
  const unsigned short* AbfB = Abf + ((size_t)(row0 >> 12) << 12) * C;

  // gather: thread (r,g) sums 8 cols [g*8, g*8+8) of row r over 16 neighbors
  {
    int r = tid >> 4, g = tid & 15;
    float s0 = 0.f, s1 = 0.f, s2 = 0.f, s3 = 0.f, s4 = 0.f, s5 = 0.f, s6 = 0.f, s7 = 0.f;
#pragma unroll
    for (int t = 0; t < K; ++t) {
      int j = ji[(r << 4) + t];
      uint4 v = *(const uint4*)(AbfB + (size_t)j * C + g * 8);
      s0 += bflo(v.x); s1 += bfhi(v.x);
      s2 += bflo(v.y); s3 += bfhi(v.y);
      s4 += bflo(v.z); s5 += bfhi(v.z);
      s6 += bflo(v.w); s7 += bfhi(v.w);
    }
    uint4 o;
    o.x = (u32)f2bf(s0) | ((u32)f2bf(s1) << 16);
    o.y = (u32)f2bf(s2) | ((u32)f2bf(s3) << 16);
    o.z = (u32)f2bf(s4) | ((u32)f2bf(s5) << 16);
    o.w = (u32)f2bf(s6) | ((u32)f2bf(s7) << 16);
    *(uint4*)(&Sl[r][g * 8]) = o;
  }
  __syncthreads();

  // MFMA: A row = lane&15, k-chunk = (lane>>4)*8 ; B col = lane&15, same k-chunk
  int lane = tid & 63, wave = tid >> 6;
  int lrow = lane & 15;
  int kgrp = (lane >> 4) * 8;
  f32x4 acc0 = {0.f, 0.f, 0.f, 0.f};
  f32x4 acc1 = {0.f, 0.f, 0.f, 0.f};
  int ct0 = wave * 2, ct1 = ct0 + 1;
  const unsigned short* abase = Abf + (size_t)(row0 + lrow) * C + kgrp;
  const unsigned short* wc0 = Wcbf + (size_t)(ct0 * 16 + lrow) * C + kgrp;
  const unsigned short* wc1 = Wcbf + (size_t)(ct1 * 16 + lrow) * C + kgrp;
  const unsigned short* wg0 = Wgbf + (size_t)(ct0 * 16 + lrow) * C + kgrp;
  const unsigned short* wg1 = Wgbf + (size_t)(ct1 * 16 + lrow) * C + kgrp;
#pragma unroll
  for (int ks = 0; ks < 4; ++ks) {
    short8_t a = *(const short8_t*)(abase + ks * 32);
    short8_t b0 = *(const short8_t*)(wc0 + ks * 32);
    short8_t b1 = *(const short8_t*)(wc1 + ks * 32);
    acc0 = __builtin_amdgcn_mfma_f32_16x16x32_bf16(a, b0, acc0, 0, 0, 0);
    acc1 = __builtin_amdgcn_mfma_f32_16x16x32_bf16(a, b1, acc1, 0, 0, 0);
  }
#pragma unroll
  for (int ks = 0; ks < 4; ++ks) {
    short8_t sf = *(const short8_t*)(&Sl[lrow][kgrp + ks * 32]);
    short8_t b0 = *(const short8_t*)(wg0 + ks * 32);
    short8_t b1 = *(const short8_t*)(wg1 + ks * 32);
    acc0 = __builtin_amdgcn_mfma_f32_16x16x32_bf16(sf, b0, acc0, 0, 0, 0);
    acc1 = __builtin_amdgcn_mfma_f32_16x16x32_bf16(sf, b1, acc1, 0, 0, 0);
  }

  // epilogue: D row=(lane>>4)*4+q, col=lane&15 (within 16x16 tile)
#pragma unroll
  for (int side = 0; side < 2; ++side) {
    int col = (side == 0 ? ct0 : ct1) * 16 + lrow;
    float bias = bc[col] + 16.0f * bg[col];
    f32x4 acc = (side == 0) ? acc0 : acc1;
#pragma unroll
    for (int q = 0; q < 4; ++q) {
      int row = row0 + (lane >> 4) * 4 + q;
      float v = (acc[q] + bias) * (1.0f / 17.0f);
      float vn = v + Pcur[(size_t)row * C + col];
      Pnxt[(size_t)row * C + col] = vn;
      if (AbfN) AbfN[(size_t)row * C + col] = f2bf(leaky(vn));
    }
  }
}

extern "C" void kernel_launch(void* const* d_in, const int* in_sizes, int n_in,
                              void* d_out, int out_size, void* d_ws, size_t ws_size,
                              hipStream_t stream) {
  const float* xyz = (const float*)d_in[0];
  const float* pts = (const float*)d_in[1];
  const float* Wc = (const float*)d_in[5];
  const float* bc = (const float*)d_in[6];
  const float* Wg = (const float*)d_in[7];
  const float* bg = (const float*)d_in[8];

  const size_t PE = (size_t)B * N * C;            // 2097152 elements
  const size_t idxB = (size_t)B * N * K * 4;      // 1 MB
  const size_t WbfB = (size_t)2 * NB * C * C * 2; // 192 KB
  char* ws = (char*)d_ws;
  float* Pa            = (float*)ws;                                  // 8 MB
  int* idx             = (int*)(ws + PE * 4);                         // 1 MB
  unsigned short* Abf0 = (unsigned short*)(ws + PE * 4 + idxB);       // 4 MB
  unsigned short* Wbf  = (unsigned short*)(ws + PE * 4 + idxB + PE * 2);
  unsigned short* Abf1 = (unsigned short*)(ws + PE * 4 + idxB + PE * 2 + WbfB);
  unsigned short* Wcbf = Wbf;
  unsigned short* Wgbf = Wbf + (size_t)NB * C * C;
  const size_t need = PE * 4 + idxB + PE * 2 + WbfB + PE * 2;  // 17.2 MB
  const bool fusedAbf = (ws_size >= need);

  hipLaunchKernelGGL(cvtW_kernel, dim3((2 * NB * C * C) / 256), dim3(256), 0, stream,
                     Wc, Wg, Wbf);
  hipLaunchKernelGGL(cvtA_kernel, dim3(PE / 8 / 256), dim3(256), 0, stream, pts, Abf0);
  hipMemcpyAsync(Pa, pts, PE * sizeof(float), hipMemcpyDeviceToDevice, stream);
  hipLaunchKernelGGL(knn_kernel, dim3(2048), dim3(1024), 0, stream, xyz, idx);

  float* cur = Pa;
  float* nxt = (float*)d_out;
  unsigned short* AbfCur = Abf0;
  unsigned short* AbfNxt = fusedAbf ? Abf1 : Abf0;
  for (int i = 0; i < NB; ++i) {
    if (!fusedAbf && i > 0) {
      hipLaunchKernelGGL(cvtA_kernel, dim3(PE / 8 / 256), dim3(256), 0, stream, cur, Abf0);
      AbfCur = Abf0;
    }
    unsigned short* an = (fusedAbf && i < NB - 1) ? AbfNxt : (unsigned short*)nullptr;
    hipLaunchKernelGGL(fused_kernel, dim3((B * N) / 16), dim3(256), 0, stream,
                       cur, AbfCur, idx, Wcbf + (size_t)i * C * C, Wgbf + (size_t)i * C * C,
                       bc + (size_t)i * C, bg + (size_t)i * C, nxt, an);
    float* tf = cur; cur = nxt; nxt = tf;
    if (fusedAbf) { unsigned short* ta = AbfCur; AbfCur = AbfNxt; AbfNxt = ta; }
  }
}

// Round 7
// 140.837 us; speedup vs baseline: 2.4409x; 1.1866x over previous
//
#include <hip/hip_runtime.h>
#include <math.h>

#define B  4
#define N  4096
#define C  128
#define K  16
#define NB 3

typedef unsigned int u32;
typedef unsigned long long u64;
typedef __attribute__((ext_vector_type(8))) short short8_t;
typedef __attribute__((ext_vector_type(4))) float f32x4;

__device__ __forceinline__ float leaky(float x) {
  return x >= 0.f ? x : 0.01f * x;
}
__device__ __forceinline__ unsigned short f2bf(float f) {
  u32 x = __float_as_uint(f);
  return (unsigned short)((x + 0x7FFFu + ((x >> 16) & 1u)) >> 16);  // RNE
}
__device__ __forceinline__ float bflo(u32 u) { return __uint_as_float(u << 16); }
__device__ __forceinline__ float bfhi(u32 u) { return __uint_as_float(u & 0xFFFF0000u); }
__device__ __forceinline__ u32 umaxu(u32 a, u32 b) { return a > b ? a : b; }

// 64-lane max reduce, pure VALU via DPP (row_shr 1/2/4/8 + row_bcast 15/31).
// Result valid in lane 63. Identity 0 (old=0, bound_ctrl off) is safe for u32 max.
__device__ __forceinline__ u32 dpp_max64(u32 v) {
  v = umaxu(v, (u32)__builtin_amdgcn_update_dpp(0, (int)v, 0x111, 0xf, 0xf, false));
  v = umaxu(v, (u32)__builtin_amdgcn_update_dpp(0, (int)v, 0x112, 0xf, 0xf, false));
  v = umaxu(v, (u32)__builtin_amdgcn_update_dpp(0, (int)v, 0x114, 0xf, 0xf, false));
  v = umaxu(v, (u32)__builtin_amdgcn_update_dpp(0, (int)v, 0x118, 0xf, 0xf, false));
  v = umaxu(v, (u32)__builtin_amdgcn_update_dpp(0, (int)v, 0x142, 0xa, 0xf, false));
  v = umaxu(v, (u32)__builtin_amdgcn_update_dpp(0, (int)v, 0x143, 0xc, 0xf, false));
  return v;
}

// ---- KNN (faithful: k+1 LARGEST sq-dists, drop first) ----
// 2048 blocks x 1024 threads (16 waves). 8 rows/block; TWO waves per row, each
// covering 2048 candidates = 32/lane. Cloud staged once in 64KB LDS as
// float4(x,y,z,sq). Per-round argmax: DPP u32 max-reduce (VALU only) +
// ballot single-match fast path; rare value-tie path does shfl min on j
// (exact jax top_k order: value desc, index asc). Each wave extracts its
// half's top-17; per-row merge = 64-lane bitonic sort of the 34 u64 keys.
__global__ __launch_bounds__(1024, 4) void knn_kernel(const float* __restrict__ xyz,
                                                      int* __restrict__ idxOut) {
  __shared__ float4 p[N];          // 64 KB
  __shared__ u64 mkeys[8][2][17];  // 2176 B
  int bidx = blockIdx.x;
  int b = bidx >> 9;               // 512 blocks per batch
  int row0 = (bidx & 511) << 3;    // 8 rows per block
  const float* src = xyz + b * N * 3;
  int tid = threadIdx.x;

  for (int e = tid; e < N; e += 1024) {
    float x = src[3 * e], y = src[3 * e + 1], z = src[3 * e + 2];
    // sq = (x*x + y*y) + z*z, exact f32 rounding, no FMA contraction
    float sq = __fadd_rn(__fadd_rn(__fmul_rn(x, x), __fmul_rn(y, y)), __fmul_rn(z, z));
    p[e] = make_float4(x, y, z, sq);
  }
  __syncthreads();

  int lane = tid & 63;
  int wave = tid >> 6;   // 0..15
  int rl = wave >> 1;    // local row 0..7
  int h = wave & 1;      // half: candidates [h*2048, h*2048+2048)
  int i = row0 + rl;     // query point within batch
  int base = (h << 11) + lane;

  float4 pi = p[i];
  float xi = pi.x, yi = pi.y, zi = pi.z, sqi = pi.w;

  u32 denc[32];
  u32 gm[4];
  int gt[4];
#pragma unroll
  for (int g = 0; g < 4; ++g) { gm[g] = 0u; gt[g] = g * 8; }

#pragma unroll
  for (int t = 0; t < 32; ++t) {
    float4 pj = p[base + (t << 6)];
    // dist = (sq_i + sq_j) - 2*dot  (reference op order, no contraction)
    float dt = __fadd_rn(__fmul_rn(xi, pj.x), __fmul_rn(yi, pj.y));
    dt = __fadd_rn(dt, __fmul_rn(zi, pj.z));
    float dd = __fsub_rn(__fadd_rn(sqi, pj.w), __fmul_rn(2.0f, dt));
    u32 bits = __float_as_uint(dd);
    u32 enc = bits ^ ((u32)(((int)bits) >> 31) | 0x80000000u);  // monotone
    denc[t] = enc;
    int g = t >> 3;
    if (enc > gm[g]) { gm[g] = enc; gt[g] = t; }  // strict > : smallest t on tie
  }

  u32 benc = 0u; int bt = 0;
#pragma unroll
  for (int g = 0; g < 4; ++g) {
    if (gm[g] > benc) { benc = gm[g]; bt = gt[g]; }
  }
  u32 bj = (u32)(base + (bt << 6));  // j of my local best

  // 17 extractions of this half's max; all stored for the merge
  for (int r = 0; r < 17; ++r) {
    u32 wmax = dpp_max64(benc);
    u32 s_wmax = (u32)__builtin_amdgcn_readlane((int)wmax, 63);
    u64 mask = __ballot(benc == s_wmax);
    int s_wj;
    if (__popcll(mask) == 1) {  // wave-uniform fast path: unique owning lane
      int l = (int)(__ffsll((long long)mask) - 1);
      s_wj = __builtin_amdgcn_readlane((int)bj, l);
    } else {  // true value tie: exact min-j among holders (rare)
      u32 jv = (benc == s_wmax) ? bj : 0xFFFFFFFFu;
#pragma unroll
      for (int off = 1; off < 64; off <<= 1) {
        u32 oj = (u32)__shfl_xor((int)jv, off, 64);
        jv = oj < jv ? oj : jv;
      }
      s_wj = (int)__builtin_amdgcn_readfirstlane((int)jv);
    }
    if (lane == 0) {
      mkeys[rl][h][r] = ((u64)s_wmax << 32) | (u32)(4095 - s_wj);
    }
    if (r == 16) break;

    int s_wt = (s_wj >> 6) & 31;    // winner slot t
    int s_wg = s_wt >> 3;
    int s_we = s_wt & 7;
    bool amW = (lane == (s_wj & 63));
#pragma unroll
    for (int g = 0; g < 4; ++g) {
      if (g == s_wg) {  // scalar branch: rescan only winner's group
        u32 nm = 0u; int nt = g * 8;
#pragma unroll
        for (int e = 0; e < 8; ++e) {
          int t = g * 8 + e;
          u32 dv = denc[t];
          if (amW && (e == s_we)) dv = 0u;  // invalidate extracted element
          denc[t] = dv;
          if (dv > nm) { nm = dv; nt = t; }
        }
        if (amW) { gm[g] = nm; gt[g] = nt; }
      }
    }
    benc = 0u; bt = 0;
#pragma unroll
    for (int g = 0; g < 4; ++g) {
      if (gm[g] > benc) { benc = gm[g]; bt = gt[g]; }
    }
    bj = (u32)(base + (bt << 6));
  }
  __syncthreads();

  // merge: wave w (<8) sorts row w's 34 keys descending; lanes 1..16 emit
  if (wave < 8) {
    u64 key = 0;
    if (lane < 17) key = mkeys[wave][0][lane];
    else if (lane < 34) key = mkeys[wave][1][lane - 17];
#pragma unroll
    for (int k = 2; k <= 64; k <<= 1) {
#pragma unroll
      for (int j = k >> 1; j > 0; j >>= 1) {
        u64 ok = __shfl_xor(key, j, 64);
        bool keepMax = ((lane & j) == 0) == ((lane & k) == 0);
        bool ogt = ok > key;
        key = (keepMax == ogt) ? ok : key;
      }
    }
    if (lane >= 1 && lane < 17) {
      int j = 4095 - (int)(u32)key;
      idxOut[((long long)(b * N + row0 + wave)) * K + lane - 1] = j;
    }
  }
}

// ---- Abf = bf16(leaky(P)) : 8 elems/thread ----
__global__ __launch_bounds__(256) void cvtA_kernel(const float* __restrict__ P,
                                                   unsigned short* __restrict__ Abf) {
  int e8 = blockIdx.x * 256 + threadIdx.x;
  const float4* p4 = (const float4*)(P + (size_t)e8 * 8);
  float4 a = p4[0], c = p4[1];
  unsigned short u0 = f2bf(leaky(a.x)), u1 = f2bf(leaky(a.y));
  unsigned short u2 = f2bf(leaky(a.z)), u3 = f2bf(leaky(a.w));
  unsigned short u4 = f2bf(leaky(c.x)), u5 = f2bf(leaky(c.y));
  unsigned short u6 = f2bf(leaky(c.z)), u7 = f2bf(leaky(c.w));
  uint4 o;
  o.x = (u32)u0 | ((u32)u1 << 16);
  o.y = (u32)u2 | ((u32)u3 << 16);
  o.z = (u32)u4 | ((u32)u5 << 16);
  o.w = (u32)u6 | ((u32)u7 << 16);
  *(uint4*)(Abf + (size_t)e8 * 8) = o;
}

// ---- W (f32) -> bf16, all 3 blocks at once ----
__global__ __launch_bounds__(256) void cvtW_kernel(const float* __restrict__ Wc,
                                                   const float* __restrict__ Wg,
                                                   unsigned short* __restrict__ Wbf) {
  int e = blockIdx.x * 256 + threadIdx.x;  // 0..98303
  if (e < NB * C * C) Wbf[e] = f2bf(Wc[e]);
  else Wbf[e] = f2bf(Wg[e - NB * C * C]);
}

// ---- fused per-block-iter: gather-sum (bf16) + dual MFMA matmul + epilogue
// grid 1024 x 256 threads (4 waves). Each workgroup: 16 rows x 128 cols out.
// out[r][o] = (leaky(P)[r]@Wc[o] + S[r]@Wg[o] + bc[o] + 16*bg[o])/17 + P[r][o]
// If AbfN != null also emits bf16(leaky(out)) for the next iteration.
__global__ __launch_bounds__(256) void fused_kernel(
    const float* __restrict__ Pcur, const unsigned short* __restrict__ Abf,
    const int* __restrict__ idx,
    const unsigned short* __restrict__ Wcbf, const unsigned short* __restrict__ Wgbf,
    const float* __restrict__ bc, const float* __restrict__ bg,
    float* __restrict__ Pnxt, unsigned short* __restrict__ AbfN) {
  __shared__ int ji[256];
  __shared__ unsigned short Sl[16][136];  // +8 pad: 272B row stride, 16B aligned
  int row0 = blockIdx.x * 16;
  int tid = threadIdx.x;
  ji[tid] = idx[row0 * K + tid];
  __syncthreads();

  // batch base for neighbor indices (idx entries are within-batch!)
  const unsigned short* AbfB = Abf + ((size_t)(row0 >> 12) << 12) * C;

  // gather: thread (r,g) sums 8 cols [g*8, g*8+8) of row r over 16 neighbors
  {
    int r = tid >> 4, g = tid & 15;
    float s0 = 0.f, s1 = 0.f, s2 = 0.f, s3 = 0.f, s4 = 0.f, s5 = 0.f, s6 = 0.f, s7 = 0.f;
#pragma unroll
    for (int t = 0; t < K; ++t) {
      int j = ji[(r << 4) + t];
      uint4 v = *(const uint4*)(AbfB + (size_t)j * C + g * 8);
      s0 += bflo(v.x); s1 += bfhi(v.x);
      s2 += bflo(v.y); s3 += bfhi(v.y);
      s4 += bflo(v.z); s5 += bfhi(v.z);
      s6 += bflo(v.w); s7 += bfhi(v.w);
    }
    uint4 o;
    o.x = (u32)f2bf(s0) | ((u32)f2bf(s1) << 16);
    o.y = (u32)f2bf(s2) | ((u32)f2bf(s3) << 16);
    o.z = (u32)f2bf(s4) | ((u32)f2bf(s5) << 16);
    o.w = (u32)f2bf(s6) | ((u32)f2bf(s7) << 16);
    *(uint4*)(&Sl[r][g * 8]) = o;
  }
  __syncthreads();

  // MFMA: A row = lane&15, k-chunk = (lane>>4)*8 ; B col = lane&15, same k-chunk
  int lane = tid & 63, wave = tid >> 6;
  int lrow = lane & 15;
  int kgrp = (lane >> 4) * 8;
  f32x4 acc0 = {0.f, 0.f, 0.f, 0.f};
  f32x4 acc1 = {0.f, 0.f, 0.f, 0.f};
  int ct0 = wave * 2, ct1 = ct0 + 1;
  const unsigned short* abase = Abf + (size_t)(row0 + lrow) * C + kgrp;
  const unsigned short* wc0 = Wcbf + (size_t)(ct0 * 16 + lrow) * C + kgrp;
  const unsigned short* wc1 = Wcbf + (size_t)(ct1 * 16 + lrow) * C + kgrp;
  const unsigned short* wg0 = Wgbf + (size_t)(ct0 * 16 + lrow) * C + kgrp;
  const unsigned short* wg1 = Wgbf + (size_t)(ct1 * 16 + lrow) * C + kgrp;
#pragma unroll
  for (int ks = 0; ks < 4; ++ks) {
    short8_t a = *(const short8_t*)(abase + ks * 32);
    short8_t b0 = *(const short8_t*)(wc0 + ks * 32);
    short8_t b1 = *(const short8_t*)(wc1 + ks * 32);
    acc0 = __builtin_amdgcn_mfma_f32_16x16x32_bf16(a, b0, acc0, 0, 0, 0);
    acc1 = __builtin_amdgcn_mfma_f32_16x16x32_bf16(a, b1, acc1, 0, 0, 0);
  }
#pragma unroll
  for (int ks = 0; ks < 4; ++ks) {
    short8_t sf = *(const short8_t*)(&Sl[lrow][kgrp + ks * 32]);
    short8_t b0 = *(const short8_t*)(wg0 + ks * 32);
    short8_t b1 = *(const short8_t*)(wg1 + ks * 32);
    acc0 = __builtin_amdgcn_mfma_f32_16x16x32_bf16(sf, b0, acc0, 0, 0, 0);
    acc1 = __builtin_amdgcn_mfma_f32_16x16x32_bf16(sf, b1, acc1, 0, 0, 0);
  }

  // epilogue: D row=(lane>>4)*4+q, col=lane&15 (within 16x16 tile)
#pragma unroll
  for (int side = 0; side < 2; ++side) {
    int col = (side == 0 ? ct0 : ct1) * 16 + lrow;
    float bias = bc[col] + 16.0f * bg[col];
    f32x4 acc = (side == 0) ? acc0 : acc1;
#pragma unroll
    for (int q = 0; q < 4; ++q) {
      int row = row0 + (lane >> 4) * 4 + q;
      float v = (acc[q] + bias) * (1.0f / 17.0f);
      float vn = v + Pcur[(size_t)row * C + col];
      Pnxt[(size_t)row * C + col] = vn;
      if (AbfN) AbfN[(size_t)row * C + col] = f2bf(leaky(vn));
    }
  }
}

extern "C" void kernel_launch(void* const* d_in, const int* in_sizes, int n_in,
                              void* d_out, int out_size, void* d_ws, size_t ws_size,
                              hipStream_t stream) {
  const float* xyz = (const float*)d_in[0];
  const float* pts = (const float*)d_in[1];
  const float* Wc = (const float*)d_in[5];
  const float* bc = (const float*)d_in[6];
  const float* Wg = (const float*)d_in[7];
  const float* bg = (const float*)d_in[8];

  const size_t PE = (size_t)B * N * C;            // 2097152 elements
  const size_t idxB = (size_t)B * N * K * 4;      // 1 MB
  const size_t WbfB = (size_t)2 * NB * C * C * 2; // 192 KB
  char* ws = (char*)d_ws;
  float* Pa            = (float*)ws;                                  // 8 MB
  int* idx             = (int*)(ws + PE * 4);                         // 1 MB
  unsigned short* Abf0 = (unsigned short*)(ws + PE * 4 + idxB);       // 4 MB
  unsigned short* Wbf  = (unsigned short*)(ws + PE * 4 + idxB + PE * 2);
  unsigned short* Abf1 = (unsigned short*)(ws + PE * 4 + idxB + PE * 2 + WbfB);
  unsigned short* Wcbf = Wbf;
  unsigned short* Wgbf = Wbf + (size_t)NB * C * C;
  const size_t need = PE * 4 + idxB + PE * 2 + WbfB + PE * 2;  // 17.2 MB
  const bool fusedAbf = (ws_size >= need);

  hipLaunchKernelGGL(cvtW_kernel, dim3((2 * NB * C * C) / 256), dim3(256), 0, stream,
                     Wc, Wg, Wbf);
  hipLaunchKernelGGL(cvtA_kernel, dim3(PE / 8 / 256), dim3(256), 0, stream, pts, Abf0);
  hipMemcpyAsync(Pa, pts, PE * sizeof(float), hipMemcpyDeviceToDevice, stream);
  hipLaunchKernelGGL(knn_kernel, dim3(2048), dim3(1024), 0, stream, xyz, idx);

  float* cur = Pa;
  float* nxt = (float*)d_out;
  unsigned short* AbfCur = Abf0;
  unsigned short* AbfNxt = fusedAbf ? Abf1 : Abf0;
  for (int i = 0; i < NB; ++i) {
    if (!fusedAbf && i > 0) {
      hipLaunchKernelGGL(cvtA_kernel, dim3(PE / 8 / 256), dim3(256), 0, stream, cur, Abf0);
      AbfCur = Abf0;
    }
    unsigned short* an = (fusedAbf && i < NB - 1) ? AbfNxt : (unsigned short*)nullptr;
    hipLaunchKernelGGL(fused_kernel, dim3((B * N) / 16), dim3(256), 0, stream,
                       cur, AbfCur, idx, Wcbf + (size_t)i * C * C, Wgbf + (size_t)i * C * C,
                       bc + (size_t)i * C, bg + (size_t)i * C, nxt, an);
    float* tf = cur; cur = nxt; nxt = tf;
    if (fusedAbf) { unsigned short* ta = AbfCur; AbfCur = AbfNxt; AbfNxt = ta; }
  }
}

// Round 8
// 137.350 us; speedup vs baseline: 2.5028x; 1.0254x over previous
//
#include <hip/hip_runtime.h>
#include <math.h>

#define B  4
#define N  4096
#define C  128
#define K  16
#define NB 3

typedef unsigned int u32;
typedef unsigned long long u64;
typedef __attribute__((ext_vector_type(8))) short short8_t;
typedef __attribute__((ext_vector_type(4))) float f32x4;

__device__ __forceinline__ float leaky(float x) {
  return x >= 0.f ? x : 0.01f * x;
}
__device__ __forceinline__ unsigned short f2bf(float f) {
  u32 x = __float_as_uint(f);
  return (unsigned short)((x + 0x7FFFu + ((x >> 16) & 1u)) >> 16);  // RNE
}
__device__ __forceinline__ float bflo(u32 u) { return __uint_as_float(u << 16); }
__device__ __forceinline__ float bfhi(u32 u) { return __uint_as_float(u & 0xFFFF0000u); }
__device__ __forceinline__ u32 umaxu(u32 a, u32 b) { return a > b ? a : b; }

// XCD-pair swizzle: blocks dispatch round-robin to the 8 XCDs by index, so
// map bidx=(q*8+x) -> batch b=x>>1 (XCD pair {2b,2b+1}), row-group 2q+(x&1).
// One batch's Abf (4MB) then lives in a single XCD's L2 for all its blocks.
__device__ __forceinline__ void swz_batch(int bidx, int* b, int* rgrp) {
  int q = bidx >> 3, x = bidx & 7;
  *b = x >> 1;
  *rgrp = (q << 1) | (x & 1);
}

// 64-lane max reduce, pure VALU via DPP (row_shr 1/2/4/8 + row_bcast 15/31).
// Result valid in lane 63. Identity 0 (old=0, bound_ctrl off) is safe for u32 max.
__device__ __forceinline__ u32 dpp_max64(u32 v) {
  v = umaxu(v, (u32)__builtin_amdgcn_update_dpp(0, (int)v, 0x111, 0xf, 0xf, false));
  v = umaxu(v, (u32)__builtin_amdgcn_update_dpp(0, (int)v, 0x112, 0xf, 0xf, false));
  v = umaxu(v, (u32)__builtin_amdgcn_update_dpp(0, (int)v, 0x114, 0xf, 0xf, false));
  v = umaxu(v, (u32)__builtin_amdgcn_update_dpp(0, (int)v, 0x118, 0xf, 0xf, false));
  v = umaxu(v, (u32)__builtin_amdgcn_update_dpp(0, (int)v, 0x142, 0xa, 0xf, false));
  v = umaxu(v, (u32)__builtin_amdgcn_update_dpp(0, (int)v, 0x143, 0xc, 0xf, false));
  return v;
}

// ---- KNN (faithful: k+1 LARGEST sq-dists, drop first) ----
// 2048 blocks x 1024 threads (16 waves). 8 rows/block; TWO waves per row, each
// covering 2048 candidates = 32/lane. Cloud staged once in 64KB LDS as
// float4(x,y,z,sq). Per-round argmax: DPP u32 max-reduce (VALU only) +
// ballot single-match fast path; rare value-tie path does shfl min on j
// (exact jax top_k order: value desc, index asc). Each wave extracts its
// half's top-17; per-row merge = 64-lane bitonic sort of the 34 u64 keys.
__global__ __launch_bounds__(1024, 4) void knn_kernel(const float* __restrict__ xyz,
                                                      int* __restrict__ idxOut) {
  __shared__ float4 p[N];          // 64 KB
  __shared__ u64 mkeys[8][2][17];  // 2176 B
  int bidx = blockIdx.x;
  int b = bidx >> 9;               // 512 blocks per batch
  int row0 = (bidx & 511) << 3;    // 8 rows per block
  const float* src = xyz + b * N * 3;
  int tid = threadIdx.x;

  for (int e = tid; e < N; e += 1024) {
    float x = src[3 * e], y = src[3 * e + 1], z = src[3 * e + 2];
    // sq = (x*x + y*y) + z*z, exact f32 rounding, no FMA contraction
    float sq = __fadd_rn(__fadd_rn(__fmul_rn(x, x), __fmul_rn(y, y)), __fmul_rn(z, z));
    p[e] = make_float4(x, y, z, sq);
  }
  __syncthreads();

  int lane = tid & 63;
  int wave = tid >> 6;   // 0..15
  int rl = wave >> 1;    // local row 0..7
  int h = wave & 1;      // half: candidates [h*2048, h*2048+2048)
  int i = row0 + rl;     // query point within batch
  int base = (h << 11) + lane;

  float4 pi = p[i];
  float xi = pi.x, yi = pi.y, zi = pi.z, sqi = pi.w;

  u32 denc[32];
  u32 gm[4];
  int gt[4];
#pragma unroll
  for (int g = 0; g < 4; ++g) { gm[g] = 0u; gt[g] = g * 8; }

#pragma unroll
  for (int t = 0; t < 32; ++t) {
    float4 pj = p[base + (t << 6)];
    // dist = (sq_i + sq_j) - 2*dot  (reference op order, no contraction)
    float dt = __fadd_rn(__fmul_rn(xi, pj.x), __fmul_rn(yi, pj.y));
    dt = __fadd_rn(dt, __fmul_rn(zi, pj.z));
    float dd = __fsub_rn(__fadd_rn(sqi, pj.w), __fmul_rn(2.0f, dt));
    u32 bits = __float_as_uint(dd);
    u32 enc = bits ^ ((u32)(((int)bits) >> 31) | 0x80000000u);  // monotone
    denc[t] = enc;
    int g = t >> 3;
    if (enc > gm[g]) { gm[g] = enc; gt[g] = t; }  // strict > : smallest t on tie
  }

  u32 benc = 0u; int bt = 0;
#pragma unroll
  for (int g = 0; g < 4; ++g) {
    if (gm[g] > benc) { benc = gm[g]; bt = gt[g]; }
  }
  u32 bj = (u32)(base + (bt << 6));  // j of my local best

  // 17 extractions of this half's max; all stored for the merge
  for (int r = 0; r < 17; ++r) {
    u32 wmax = dpp_max64(benc);
    u32 s_wmax = (u32)__builtin_amdgcn_readlane((int)wmax, 63);
    u64 mask = __ballot(benc == s_wmax);
    int s_wj;
    if (__popcll(mask) == 1) {  // wave-uniform fast path: unique owning lane
      int l = (int)(__ffsll((long long)mask) - 1);
      s_wj = __builtin_amdgcn_readlane((int)bj, l);
    } else {  // true value tie: exact min-j among holders (rare)
      u32 jv = (benc == s_wmax) ? bj : 0xFFFFFFFFu;
#pragma unroll
      for (int off = 1; off < 64; off <<= 1) {
        u32 oj = (u32)__shfl_xor((int)jv, off, 64);
        jv = oj < jv ? oj : jv;
      }
      s_wj = (int)__builtin_amdgcn_readfirstlane((int)jv);
    }
    if (lane == 0) {
      mkeys[rl][h][r] = ((u64)s_wmax << 32) | (u32)(4095 - s_wj);
    }
    if (r == 16) break;

    int s_wt = (s_wj >> 6) & 31;    // winner slot t
    int s_wg = s_wt >> 3;
    int s_we = s_wt & 7;
    bool amW = (lane == (s_wj & 63));
#pragma unroll
    for (int g = 0; g < 4; ++g) {
      if (g == s_wg) {  // scalar branch: rescan only winner's group
        u32 nm = 0u; int nt = g * 8;
#pragma unroll
        for (int e = 0; e < 8; ++e) {
          int t = g * 8 + e;
          u32 dv = denc[t];
          if (amW && (e == s_we)) dv = 0u;  // invalidate extracted element
          denc[t] = dv;
          if (dv > nm) { nm = dv; nt = t; }
        }
        if (amW) { gm[g] = nm; gt[g] = nt; }
      }
    }
    benc = 0u; bt = 0;
#pragma unroll
    for (int g = 0; g < 4; ++g) {
      if (gm[g] > benc) { benc = gm[g]; bt = gt[g]; }
    }
    bj = (u32)(base + (bt << 6));
  }
  __syncthreads();

  // merge: wave w (<8) sorts row w's 34 keys descending; lanes 1..16 emit
  if (wave < 8) {
    u64 key = 0;
    if (lane < 17) key = mkeys[wave][0][lane];
    else if (lane < 34) key = mkeys[wave][1][lane - 17];
#pragma unroll
    for (int k = 2; k <= 64; k <<= 1) {
#pragma unroll
      for (int j = k >> 1; j > 0; j >>= 1) {
        u64 ok = __shfl_xor(key, j, 64);
        bool keepMax = ((lane & j) == 0) == ((lane & k) == 0);
        bool ogt = ok > key;
        key = (keepMax == ogt) ? ok : key;
      }
    }
    if (lane >= 1 && lane < 17) {
      int j = 4095 - (int)(u32)key;
      idxOut[((long long)(b * N + row0 + wave)) * K + lane - 1] = j;
    }
  }
}

// ---- Abf = bf16(leaky(P)) : XCD-pair swizzled (writer XCD == reader XCD) ----
// 1024 blocks x 256; block covers 16 rows of its batch.
__global__ __launch_bounds__(256) void cvtA_kernel(const float* __restrict__ P,
                                                   unsigned short* __restrict__ Abf) {
  int b, rgrp;
  swz_batch(blockIdx.x, &b, &rgrp);
  int tid = threadIdx.x;
  size_t off = ((size_t)b * N + rgrp * 16 + (tid >> 4)) * C + (tid & 15) * 8;
  const float4* p4 = (const float4*)(P + off);
  float4 a = p4[0], c = p4[1];
  unsigned short u0 = f2bf(leaky(a.x)), u1 = f2bf(leaky(a.y));
  unsigned short u2 = f2bf(leaky(a.z)), u3 = f2bf(leaky(a.w));
  unsigned short u4 = f2bf(leaky(c.x)), u5 = f2bf(leaky(c.y));
  unsigned short u6 = f2bf(leaky(c.z)), u7 = f2bf(leaky(c.w));
  uint4 o;
  o.x = (u32)u0 | ((u32)u1 << 16);
  o.y = (u32)u2 | ((u32)u3 << 16);
  o.z = (u32)u4 | ((u32)u5 << 16);
  o.w = (u32)u6 | ((u32)u7 << 16);
  *(uint4*)(Abf + off) = o;
}

// ---- W (f32) -> bf16, all 3 blocks at once ----
__global__ __launch_bounds__(256) void cvtW_kernel(const float* __restrict__ Wc,
                                                   const float* __restrict__ Wg,
                                                   unsigned short* __restrict__ Wbf) {
  int e = blockIdx.x * 256 + threadIdx.x;  // 0..98303
  if (e < NB * C * C) Wbf[e] = f2bf(Wc[e]);
  else Wbf[e] = f2bf(Wg[e - NB * C * C]);
}

// ---- fused per-block-iter: gather-sum (bf16) + dual MFMA matmul + epilogue
// grid 1024 x 256 threads (4 waves), XCD-pair swizzled: block = 16 rows of one
// batch; that batch's Abf (4MB) stays resident in its XCD pair's L2.
// out[r][o] = (leaky(P)[r]@Wc[o] + S[r]@Wg[o] + bc[o] + 16*bg[o])/17 + P[r][o]
// If AbfN != null also emits bf16(leaky(out)) for the next iteration.
__global__ __launch_bounds__(256) void fused_kernel(
    const float* __restrict__ Pcur, const unsigned short* __restrict__ Abf,
    const int* __restrict__ idx,
    const unsigned short* __restrict__ Wcbf, const unsigned short* __restrict__ Wgbf,
    const float* __restrict__ bc, const float* __restrict__ bg,
    float* __restrict__ Pnxt, unsigned short* __restrict__ AbfN) {
  __shared__ int ji[256];
  __shared__ unsigned short Sl[16][136];  // +8 pad: 272B row stride, 16B aligned
  int bb, rgrp;
  swz_batch(blockIdx.x, &bb, &rgrp);
  int row0 = bb * N + rgrp * 16;  // global row
  int tid = threadIdx.x;
  ji[tid] = idx[row0 * K + tid];
  __syncthreads();

  // batch base for neighbor indices (idx entries are within-batch!)
  const unsigned short* AbfB = Abf + ((size_t)bb << 12) * C;

  // gather: thread (r,g) sums 8 cols [g*8, g*8+8) of row r over 16 neighbors
  {
    int r = tid >> 4, g = tid & 15;
    float s0 = 0.f, s1 = 0.f, s2 = 0.f, s3 = 0.f, s4 = 0.f, s5 = 0.f, s6 = 0.f, s7 = 0.f;
#pragma unroll
    for (int t = 0; t < K; ++t) {
      int j = ji[(r << 4) + t];
      uint4 v = *(const uint4*)(AbfB + (size_t)j * C + g * 8);
      s0 += bflo(v.x); s1 += bfhi(v.x);
      s2 += bflo(v.y); s3 += bfhi(v.y);
      s4 += bflo(v.z); s5 += bfhi(v.z);
      s6 += bflo(v.w); s7 += bfhi(v.w);
    }
    uint4 o;
    o.x = (u32)f2bf(s0) | ((u32)f2bf(s1) << 16);
    o.y = (u32)f2bf(s2) | ((u32)f2bf(s3) << 16);
    o.z = (u32)f2bf(s4) | ((u32)f2bf(s5) << 16);
    o.w = (u32)f2bf(s6) | ((u32)f2bf(s7) << 16);
    *(uint4*)(&Sl[r][g * 8]) = o;
  }
  __syncthreads();

  // MFMA: A row = lane&15, k-chunk = (lane>>4)*8 ; B col = lane&15, same k-chunk
  int lane = tid & 63, wave = tid >> 6;
  int lrow = lane & 15;
  int kgrp = (lane >> 4) * 8;
  f32x4 acc0 = {0.f, 0.f, 0.f, 0.f};
  f32x4 acc1 = {0.f, 0.f, 0.f, 0.f};
  int ct0 = wave * 2, ct1 = ct0 + 1;
  const unsigned short* abase = Abf + (size_t)(row0 + lrow) * C + kgrp;
  const unsigned short* wc0 = Wcbf + (size_t)(ct0 * 16 + lrow) * C + kgrp;
  const unsigned short* wc1 = Wcbf + (size_t)(ct1 * 16 + lrow) * C + kgrp;
  const unsigned short* wg0 = Wgbf + (size_t)(ct0 * 16 + lrow) * C + kgrp;
  const unsigned short* wg1 = Wgbf + (size_t)(ct1 * 16 + lrow) * C + kgrp;
#pragma unroll
  for (int ks = 0; ks < 4; ++ks) {
    short8_t a = *(const short8_t*)(abase + ks * 32);
    short8_t b0 = *(const short8_t*)(wc0 + ks * 32);
    short8_t b1 = *(const short8_t*)(wc1 + ks * 32);
    acc0 = __builtin_amdgcn_mfma_f32_16x16x32_bf16(a, b0, acc0, 0, 0, 0);
    acc1 = __builtin_amdgcn_mfma_f32_16x16x32_bf16(a, b1, acc1, 0, 0, 0);
  }
#pragma unroll
  for (int ks = 0; ks < 4; ++ks) {
    short8_t sf = *(const short8_t*)(&Sl[lrow][kgrp + ks * 32]);
    short8_t b0 = *(const short8_t*)(wg0 + ks * 32);
    short8_t b1 = *(const short8_t*)(wg1 + ks * 32);
    acc0 = __builtin_amdgcn_mfma_f32_16x16x32_bf16(sf, b0, acc0, 0, 0, 0);
    acc1 = __builtin_amdgcn_mfma_f32_16x16x32_bf16(sf, b1, acc1, 0, 0, 0);
  }

  // epilogue: D row=(lane>>4)*4+q, col=lane&15 (within 16x16 tile)
#pragma unroll
  for (int side = 0; side < 2; ++side) {
    int col = (side == 0 ? ct0 : ct1) * 16 + lrow;
    float bias = bc[col] + 16.0f * bg[col];
    f32x4 acc = (side == 0) ? acc0 : acc1;
#pragma unroll
    for (int q = 0; q < 4; ++q) {
      int row = row0 + (lane >> 4) * 4 + q;
      float v = (acc[q] + bias) * (1.0f / 17.0f);
      float vn = v + Pcur[(size_t)row * C + col];
      Pnxt[(size_t)row * C + col] = vn;
      if (AbfN) AbfN[(size_t)row * C + col] = f2bf(leaky(vn));
    }
  }
}

extern "C" void kernel_launch(void* const* d_in, const int* in_sizes, int n_in,
                              void* d_out, int out_size, void* d_ws, size_t ws_size,
                              hipStream_t stream) {
  const float* xyz = (const float*)d_in[0];
  const float* pts = (const float*)d_in[1];
  const float* Wc = (const float*)d_in[5];
  const float* bc = (const float*)d_in[6];
  const float* Wg = (const float*)d_in[7];
  const float* bg = (const float*)d_in[8];

  const size_t PE = (size_t)B * N * C;            // 2097152 elements
  const size_t idxB = (size_t)B * N * K * 4;      // 1 MB
  const size_t WbfB = (size_t)2 * NB * C * C * 2; // 192 KB
  char* ws = (char*)d_ws;
  float* Pa            = (float*)ws;                                  // 8 MB
  int* idx             = (int*)(ws + PE * 4);                         // 1 MB
  unsigned short* Abf0 = (unsigned short*)(ws + PE * 4 + idxB);       // 4 MB
  unsigned short* Wbf  = (unsigned short*)(ws + PE * 4 + idxB + PE * 2);
  unsigned short* Abf1 = (unsigned short*)(ws + PE * 4 + idxB + PE * 2 + WbfB);
  unsigned short* Wcbf = Wbf;
  unsigned short* Wgbf = Wbf + (size_t)NB * C * C;
  const size_t need = PE * 4 + idxB + PE * 2 + WbfB + PE * 2;  // 17.2 MB
  const bool fusedAbf = (ws_size >= need);

  hipLaunchKernelGGL(cvtW_kernel, dim3((2 * NB * C * C) / 256), dim3(256), 0, stream,
                     Wc, Wg, Wbf);
  hipLaunchKernelGGL(cvtA_kernel, dim3(1024), dim3(256), 0, stream, pts, Abf0);
  hipLaunchKernelGGL(knn_kernel, dim3(2048), dim3(1024), 0, stream, xyz, idx);

  // ping-pong: pts (read-only) -> d_out -> Pa -> d_out
  const float* cur = pts;
  float* nxt = (float*)d_out;
  unsigned short* AbfCur = Abf0;
  unsigned short* AbfNxt = fusedAbf ? Abf1 : Abf0;
  for (int i = 0; i < NB; ++i) {
    if (!fusedAbf && i > 0) {
      hipLaunchKernelGGL(cvtA_kernel, dim3(1024), dim3(256), 0, stream, cur, Abf0);
      AbfCur = Abf0;
    }
    unsigned short* an = (fusedAbf && i < NB - 1) ? AbfNxt : (unsigned short*)nullptr;
    hipLaunchKernelGGL(fused_kernel, dim3(1024), dim3(256), 0, stream,
                       cur, AbfCur, idx, Wcbf + (size_t)i * C * C, Wgbf + (size_t)i * C * C,
                       bc + (size_t)i * C, bg + (size_t)i * C, nxt, an);
    cur = nxt;
    nxt = (i == 0) ? Pa : (float*)d_out;
    if (fusedAbf) { unsigned short* ta = AbfCur; AbfCur = AbfNxt; AbfNxt = ta; }
  }
}

// Round 9
// 116.903 us; speedup vs baseline: 2.9406x; 1.1749x over previous
//
#include <hip/hip_runtime.h>
#include <math.h>

#define B  4
#define N  4096
#define C  128
#define K  16
#define NB 3

typedef unsigned int u32;
typedef unsigned long long u64;
typedef __attribute__((ext_vector_type(8))) short short8_t;
typedef __attribute__((ext_vector_type(4))) float f32x4;

__device__ __forceinline__ float leaky(float x) {
  return x >= 0.f ? x : 0.01f * x;
}
__device__ __forceinline__ unsigned short f2bf(float f) {
  u32 x = __float_as_uint(f);
  return (unsigned short)((x + 0x7FFFu + ((x >> 16) & 1u)) >> 16);  // RNE
}
__device__ __forceinline__ float bflo(u32 u) { return __uint_as_float(u << 16); }
__device__ __forceinline__ float bfhi(u32 u) { return __uint_as_float(u & 0xFFFF0000u); }
__device__ __forceinline__ u32 umaxu(u32 a, u32 b) { return a > b ? a : b; }

// XCD-pair swizzle for the fused pipeline (kept from round 7; harmless).
__device__ __forceinline__ void swz_batch(int bidx, int* b, int* rgrp) {
  int q = bidx >> 3, x = bidx & 7;
  *b = x >> 1;
  *rgrp = (q << 1) | (x & 1);
}

// 64-lane max reduce, pure VALU via DPP. Result valid in lane 63.
__device__ __forceinline__ u32 dpp_max64(u32 v) {
  v = umaxu(v, (u32)__builtin_amdgcn_update_dpp(0, (int)v, 0x111, 0xf, 0xf, false));
  v = umaxu(v, (u32)__builtin_amdgcn_update_dpp(0, (int)v, 0x112, 0xf, 0xf, false));
  v = umaxu(v, (u32)__builtin_amdgcn_update_dpp(0, (int)v, 0x114, 0xf, 0xf, false));
  v = umaxu(v, (u32)__builtin_amdgcn_update_dpp(0, (int)v, 0x118, 0xf, 0xf, false));
  v = umaxu(v, (u32)__builtin_amdgcn_update_dpp(0, (int)v, 0x142, 0xa, 0xf, false));
  v = umaxu(v, (u32)__builtin_amdgcn_update_dpp(0, (int)v, 0x143, 0xc, 0xf, false));
  return v;
}

// ---- KNN (faithful: k+1 LARGEST sq-dists, drop first) ----
// 2048 blocks x 512 threads (8 waves). ONE wave per row, 64 candidates/lane.
// Threshold-select: (1) per-lane max tracked in the distance pass; (2) bitonic
// sort of the 64 lane-max keys -> tau = 17th-largest lane-max (guarantees >=17
// survivors); (3) ballot-compaction of candidates with enc >= tau into LDS
// (E[survivors]~20); (4) bitonic sort of survivors; ranks 1..16 are output
// (rank 0 = dropped max). Key (enc<<32)|(4095-j) == jax top_k order
// (value desc, index asc). Iterative fallback if survivors > 64 (never on
// random data; recomputes from LDS so denc[] stays register-resident).
__global__ __launch_bounds__(512, 4) void knn_kernel(const float* __restrict__ xyz,
                                                     int* __restrict__ idxOut) {
  __shared__ float4 p[N];       // 64 KB
  __shared__ u64 surv[8][64];   // 4 KB survivor buffer, per wave
  int bidx = blockIdx.x;
  int b = bidx >> 9;            // 512 blocks per batch
  int row0 = (bidx & 511) << 3; // 8 rows per block
  const float* src = xyz + b * N * 3;
  int tid = threadIdx.x;

  for (int e = tid; e < N; e += 512) {
    float x = src[3 * e], y = src[3 * e + 1], z = src[3 * e + 2];
    // sq = (x*x + y*y) + z*z, exact f32 rounding, no FMA contraction
    float sq = __fadd_rn(__fadd_rn(__fmul_rn(x, x), __fmul_rn(y, y)), __fmul_rn(z, z));
    p[e] = make_float4(x, y, z, sq);
  }
  __syncthreads();

  int lane = tid & 63;
  int wave = tid >> 6;   // 0..7 = local row
  int i = row0 + wave;   // query point within batch

  float4 pi = p[i];
  float xi = pi.x, yi = pi.y, zi = pi.z, sqi = pi.w;

  // Phase A: distances + per-lane argmax
  u32 denc[64];
  u32 lmax = 0u; int lt = 0;
#pragma unroll
  for (int t = 0; t < 64; ++t) {
    float4 pj = p[lane + (t << 6)];
    // dist = (sq_i + sq_j) - 2*dot  (reference op order, no contraction)
    float dt = __fadd_rn(__fmul_rn(xi, pj.x), __fmul_rn(yi, pj.y));
    dt = __fadd_rn(dt, __fmul_rn(zi, pj.z));
    float dd = __fsub_rn(__fadd_rn(sqi, pj.w), __fmul_rn(2.0f, dt));
    u32 bits = __float_as_uint(dd);
    u32 enc = bits ^ ((u32)(((int)bits) >> 31) | 0x80000000u);  // monotone
    denc[t] = enc;
    if (enc > lmax) { lmax = enc; lt = t; }  // strict > : smallest t on tie
  }

  // Phase B: sort the 64 lane-max keys descending; tau = 17th largest value
  u64 skey = ((u64)lmax << 32) | (u32)(4095 - (lane + (lt << 6)));
#pragma unroll
  for (int k2 = 2; k2 <= 64; k2 <<= 1) {
#pragma unroll
    for (int jj = k2 >> 1; jj > 0; jj >>= 1) {
      u64 ok = __shfl_xor(skey, jj, 64);
      bool keepMax = ((lane & jj) == 0) == ((lane & k2) == 0);
      skey = (keepMax == (ok > skey)) ? ok : skey;
    }
  }
  u64 k16 = __shfl(skey, 16, 64);
  u32 tau = (u32)(k16 >> 32);

  // Phase C: ballot-compact survivors (enc >= tau) into surv[wave][]
  int total = 0;
#pragma unroll
  for (int t = 0; t < 64; ++t) {
    bool pred = (denc[t] >= tau);
    u64 bal = __ballot(pred);
    if (bal != 0ull) {  // wave-uniform skip of empty slots
      int pos = total + (int)__builtin_amdgcn_mbcnt_hi(
                            (u32)(bal >> 32),
                            __builtin_amdgcn_mbcnt_lo((u32)bal, 0u));
      if (pred && pos < 64) {
        surv[wave][pos] = ((u64)denc[t] << 32) | (u32)(4095 - (lane + (t << 6)));
      }
      total += (int)__popcll(bal);
    }
  }

  if (total <= 64) {
    // Phase D: sort survivors descending (zeros pad to the end), emit 1..16.
    // Same-wave LDS write->read: DS pipe is in-order per wave; compiler
    // preserves may-aliasing LDS op order.
    u64 sk = (lane < total) ? surv[wave][lane] : 0ull;
#pragma unroll
    for (int k2 = 2; k2 <= 64; k2 <<= 1) {
#pragma unroll
      for (int jj = k2 >> 1; jj > 0; jj >>= 1) {
        u64 ok = __shfl_xor(sk, jj, 64);
        bool keepMax = ((lane & jj) == 0) == ((lane & k2) == 0);
        sk = (keepMax == (ok > sk)) ? ok : sk;
      }
    }
    if (lane >= 1 && lane < 17) {
      idxOut[((long long)(b * N + i)) * K + lane - 1] = 4095 - (int)(u32)sk;
    }
  } else {
    // Fallback (degenerate ties; never on this input): exact iterative
    // extraction, recomputing from LDS so denc[] is never dynamically indexed.
    u32 cmax = lmax; u32 ct = (u32)lt;
    u64 elim = 0ull;
    for (int r = 0; r < 17; ++r) {
      u32 wmax = dpp_max64(cmax);
      u32 s_wmax = (u32)__builtin_amdgcn_readlane((int)wmax, 63);
      u64 mask = __ballot(cmax == s_wmax);
      int s_wj;
      if (__popcll(mask) == 1) {
        int l = (int)(__ffsll((long long)mask) - 1);
        int myj = lane + ((int)ct << 6);
        s_wj = __builtin_amdgcn_readlane(myj, l);
      } else {
        u32 jv = (cmax == s_wmax) ? (u32)(lane + ((int)ct << 6)) : 0xFFFFFFFFu;
#pragma unroll
        for (int off = 1; off < 64; off <<= 1) {
          u32 oj = (u32)__shfl_xor((int)jv, off, 64);
          jv = oj < jv ? oj : jv;
        }
        s_wj = (int)__builtin_amdgcn_readfirstlane((int)jv);
      }
      if (r > 0 && lane == 0)
        idxOut[((long long)(b * N + i)) * K + (r - 1)] = s_wj;
      if (r == 16) break;
      if (lane == (s_wj & 63)) {
        elim |= 1ull << (s_wj >> 6);
        cmax = 0u; ct = 0u;
        for (int t = 0; t < 64; ++t) {  // runtime loop over LDS (no denc use)
          if (elim & (1ull << t)) continue;
          float4 pj = p[lane + (t << 6)];
          float dt2 = __fadd_rn(__fmul_rn(xi, pj.x), __fmul_rn(yi, pj.y));
          dt2 = __fadd_rn(dt2, __fmul_rn(zi, pj.z));
          float dd = __fsub_rn(__fadd_rn(sqi, pj.w), __fmul_rn(2.0f, dt2));
          u32 bits = __float_as_uint(dd);
          u32 enc = bits ^ ((u32)(((int)bits) >> 31) | 0x80000000u);
          if (enc > cmax) { cmax = enc; ct = (u32)t; }
        }
      }
    }
  }
}

// ---- Abf = bf16(leaky(P)) : XCD-pair swizzled ----
__global__ __launch_bounds__(256) void cvtA_kernel(const float* __restrict__ P,
                                                   unsigned short* __restrict__ Abf) {
  int b, rgrp;
  swz_batch(blockIdx.x, &b, &rgrp);
  int tid = threadIdx.x;
  size_t off = ((size_t)b * N + rgrp * 16 + (tid >> 4)) * C + (tid & 15) * 8;
  const float4* p4 = (const float4*)(P + off);
  float4 a = p4[0], c = p4[1];
  unsigned short u0 = f2bf(leaky(a.x)), u1 = f2bf(leaky(a.y));
  unsigned short u2 = f2bf(leaky(a.z)), u3 = f2bf(leaky(a.w));
  unsigned short u4 = f2bf(leaky(c.x)), u5 = f2bf(leaky(c.y));
  unsigned short u6 = f2bf(leaky(c.z)), u7 = f2bf(leaky(c.w));
  uint4 o;
  o.x = (u32)u0 | ((u32)u1 << 16);
  o.y = (u32)u2 | ((u32)u3 << 16);
  o.z = (u32)u4 | ((u32)u5 << 16);
  o.w = (u32)u6 | ((u32)u7 << 16);
  *(uint4*)(Abf + off) = o;
}

// ---- W (f32) -> bf16, all 3 blocks at once ----
__global__ __launch_bounds__(256) void cvtW_kernel(const float* __restrict__ Wc,
                                                   const float* __restrict__ Wg,
                                                   unsigned short* __restrict__ Wbf) {
  int e = blockIdx.x * 256 + threadIdx.x;  // 0..98303
  if (e < NB * C * C) Wbf[e] = f2bf(Wc[e]);
  else Wbf[e] = f2bf(Wg[e - NB * C * C]);
}

// ---- fused per-block-iter: gather-sum (bf16) + dual MFMA matmul + epilogue
__global__ __launch_bounds__(256) void fused_kernel(
    const float* __restrict__ Pcur, const unsigned short* __restrict__ Abf,
    const int* __restrict__ idx,
    const unsigned short* __restrict__ Wcbf, const unsigned short* __restrict__ Wgbf,
    const float* __restrict__ bc, const float* __restrict__ bg,
    float* __restrict__ Pnxt, unsigned short* __restrict__ AbfN) {
  __shared__ int ji[256];
  __shared__ unsigned short Sl[16][136];  // +8 pad: 272B row stride, 16B aligned
  int bb, rgrp;
  swz_batch(blockIdx.x, &bb, &rgrp);
  int row0 = bb * N + rgrp * 16;  // global row
  int tid = threadIdx.x;
  ji[tid] = idx[row0 * K + tid];
  __syncthreads();

  // batch base for neighbor indices (idx entries are within-batch!)
  const unsigned short* AbfB = Abf + ((size_t)bb << 12) * C;

  // gather: thread (r,g) sums 8 cols [g*8, g*8+8) of row r over 16 neighbors
  {
    int r = tid >> 4, g = tid & 15;
    float s0 = 0.f, s1 = 0.f, s2 = 0.f, s3 = 0.f, s4 = 0.f, s5 = 0.f, s6 = 0.f, s7 = 0.f;
#pragma unroll
    for (int t = 0; t < K; ++t) {
      int j = ji[(r << 4) + t];
      uint4 v = *(const uint4*)(AbfB + (size_t)j * C + g * 8);
      s0 += bflo(v.x); s1 += bfhi(v.x);
      s2 += bflo(v.y); s3 += bfhi(v.y);
      s4 += bflo(v.z); s5 += bfhi(v.z);
      s6 += bflo(v.w); s7 += bfhi(v.w);
    }
    uint4 o;
    o.x = (u32)f2bf(s0) | ((u32)f2bf(s1) << 16);
    o.y = (u32)f2bf(s2) | ((u32)f2bf(s3) << 16);
    o.z = (u32)f2bf(s4) | ((u32)f2bf(s5) << 16);
    o.w = (u32)f2bf(s6) | ((u32)f2bf(s7) << 16);
    *(uint4*)(&Sl[r][g * 8]) = o;
  }
  __syncthreads();

  // MFMA: A row = lane&15, k-chunk = (lane>>4)*8 ; B col = lane&15, same k-chunk
  int lane = tid & 63, wave = tid >> 6;
  int lrow = lane & 15;
  int kgrp = (lane >> 4) * 8;
  f32x4 acc0 = {0.f, 0.f, 0.f, 0.f};
  f32x4 acc1 = {0.f, 0.f, 0.f, 0.f};
  int ct0 = wave * 2, ct1 = ct0 + 1;
  const unsigned short* abase = Abf + (size_t)(row0 + lrow) * C + kgrp;
  const unsigned short* wc0 = Wcbf + (size_t)(ct0 * 16 + lrow) * C + kgrp;
  const unsigned short* wc1 = Wcbf + (size_t)(ct1 * 16 + lrow) * C + kgrp;
  const unsigned short* wg0 = Wgbf + (size_t)(ct0 * 16 + lrow) * C + kgrp;
  const unsigned short* wg1 = Wgbf + (size_t)(ct1 * 16 + lrow) * C + kgrp;
#pragma unroll
  for (int ks = 0; ks < 4; ++ks) {
    short8_t a = *(const short8_t*)(abase + ks * 32);
    short8_t b0 = *(const short8_t*)(wc0 + ks * 32);
    short8_t b1 = *(const short8_t*)(wc1 + ks * 32);
    acc0 = __builtin_amdgcn_mfma_f32_16x16x32_bf16(a, b0, acc0, 0, 0, 0);
    acc1 = __builtin_amdgcn_mfma_f32_16x16x32_bf16(a, b1, acc1, 0, 0, 0);
  }
#pragma unroll
  for (int ks = 0; ks < 4; ++ks) {
    short8_t sf = *(const short8_t*)(&Sl[lrow][kgrp + ks * 32]);
    short8_t b0 = *(const short8_t*)(wg0 + ks * 32);
    short8_t b1 = *(const short8_t*)(wg1 + ks * 32);
    acc0 = __builtin_amdgcn_mfma_f32_16x16x32_bf16(sf, b0, acc0, 0, 0, 0);
    acc1 = __builtin_amdgcn_mfma_f32_16x16x32_bf16(sf, b1, acc1, 0, 0, 0);
  }

  // epilogue: D row=(lane>>4)*4+q, col=lane&15 (within 16x16 tile)
#pragma unroll
  for (int side = 0; side < 2; ++side) {
    int col = (side == 0 ? ct0 : ct1) * 16 + lrow;
    float bias = bc[col] + 16.0f * bg[col];
    f32x4 acc = (side == 0) ? acc0 : acc1;
#pragma unroll
    for (int q = 0; q < 4; ++q) {
      int row = row0 + (lane >> 4) * 4 + q;
      float v = (acc[q] + bias) * (1.0f / 17.0f);
      float vn = v + Pcur[(size_t)row * C + col];
      Pnxt[(size_t)row * C + col] = vn;
      if (AbfN) AbfN[(size_t)row * C + col] = f2bf(leaky(vn));
    }
  }
}

extern "C" void kernel_launch(void* const* d_in, const int* in_sizes, int n_in,
                              void* d_out, int out_size, void* d_ws, size_t ws_size,
                              hipStream_t stream) {
  const float* xyz = (const float*)d_in[0];
  const float* pts = (const float*)d_in[1];
  const float* Wc = (const float*)d_in[5];
  const float* bc = (const float*)d_in[6];
  const float* Wg = (const float*)d_in[7];
  const float* bg = (const float*)d_in[8];

  const size_t PE = (size_t)B * N * C;            // 2097152 elements
  const size_t idxB = (size_t)B * N * K * 4;      // 1 MB
  const size_t WbfB = (size_t)2 * NB * C * C * 2; // 192 KB
  char* ws = (char*)d_ws;
  float* Pa            = (float*)ws;                                  // 8 MB
  int* idx             = (int*)(ws + PE * 4);                         // 1 MB
  unsigned short* Abf0 = (unsigned short*)(ws + PE * 4 + idxB);       // 4 MB
  unsigned short* Wbf  = (unsigned short*)(ws + PE * 4 + idxB + PE * 2);
  unsigned short* Abf1 = (unsigned short*)(ws + PE * 4 + idxB + PE * 2 + WbfB);
  unsigned short* Wcbf = Wbf;
  unsigned short* Wgbf = Wbf + (size_t)NB * C * C;
  const size_t need = PE * 4 + idxB + PE * 2 + WbfB + PE * 2;  // 17.2 MB
  const bool fusedAbf = (ws_size >= need);

  hipLaunchKernelGGL(cvtW_kernel, dim3((2 * NB * C * C) / 256), dim3(256), 0, stream,
                     Wc, Wg, Wbf);
  hipLaunchKernelGGL(cvtA_kernel, dim3(1024), dim3(256), 0, stream, pts, Abf0);
  hipLaunchKernelGGL(knn_kernel, dim3(2048), dim3(512), 0, stream, xyz, idx);

  // ping-pong: pts (read-only) -> d_out -> Pa -> d_out
  const float* cur = pts;
  float* nxt = (float*)d_out;
  unsigned short* AbfCur = Abf0;
  unsigned short* AbfNxt = fusedAbf ? Abf1 : Abf0;
  for (int i = 0; i < NB; ++i) {
    if (!fusedAbf && i > 0) {
      hipLaunchKernelGGL(cvtA_kernel, dim3(1024), dim3(256), 0, stream, cur, Abf0);
      AbfCur = Abf0;
    }
    unsigned short* an = (fusedAbf && i < NB - 1) ? AbfNxt : (unsigned short*)nullptr;
    hipLaunchKernelGGL(fused_kernel, dim3(1024), dim3(256), 0, stream,
                       cur, AbfCur, idx, Wcbf + (size_t)i * C * C, Wgbf + (size_t)i * C * C,
                       bc + (size_t)i * C, bg + (size_t)i * C, nxt, an);
    cur = nxt;
    nxt = (i == 0) ? Pa : (float*)d_out;
    if (fusedAbf) { unsigned short* ta = AbfCur; AbfCur = AbfNxt; AbfNxt = ta; }
  }
}